// Round 4
// baseline (637.152 us; speedup 1.0000x reference)
//
#include <hip/hip_runtime.h>
#include <math.h>

// ---------------------------------------------------------------------------
// B=16, T=4096, D=256, V=256, PATCH=4, Np=1024, BN=16384
// All GEMMs: C[M,N] = A[M,256] @ Bt[N,256]^T (+epilogue), bf16 inputs, K=256.
// ---------------------------------------------------------------------------

typedef __bf16 bf16_t;
typedef bf16_t bf16x8 __attribute__((ext_vector_type(8)));
typedef bf16_t bf16x4 __attribute__((ext_vector_type(4)));
typedef float f32x4 __attribute__((ext_vector_type(4)));

#define GF_BIAS 1
#define GF_GELU 4
#define GF_RES 8
#define GF_F32OUT 32

__device__ __forceinline__ float gelu_exact(float x) {
  return 0.5f * x * (1.0f + erff(x * 0.7071067811865475f));
}

__device__ __forceinline__ float sigm(float x) { return 1.f / (1.f + expf(-x)); }

__device__ __forceinline__ float wave_sum(float v) {
#pragma unroll
  for (int o = 32; o; o >>= 1) v += __shfl_xor(v, o, 64);
  return v;
}

__device__ __forceinline__ void gload16(const void* g, void* l) {
  __builtin_amdgcn_global_load_lds(
      (const __attribute__((address_space(1))) void*)g,
      (__attribute__((address_space(3))) void*)l, 16, 0, 0);
}

// ---------------- bf16 MFMA GEMM: 128x128 tile, 4 waves, BK=64 --------------
template<int FLAGS>
__global__ __launch_bounds__(256)
void gemm_bt(const bf16_t* __restrict__ A, const bf16_t* __restrict__ Bt,
             void* __restrict__ Cv, const float* __restrict__ bias,
             const bf16_t* __restrict__ res,
             int lda, int ldb, int ldc, int ldr)
{
  __shared__ __align__(16) bf16_t As[128][64];
  __shared__ __align__(16) bf16_t Bs[128][64];
  const int m0 = blockIdx.x * 128, n0 = blockIdx.y * 128;
  const int tid = threadIdx.x, lane = tid & 63, wave = tid >> 6;
  const int wm = (wave >> 1) << 6, wn = (wave & 1) << 6;
  const int lr = lane & 15, lg = lane >> 4;

  const int srow = wave * 32 + (lane >> 3);
  const int scol = (lane & 7) * 8;
  const bf16_t* ga = A  + (long long)(m0 + srow) * lda + scol;
  const bf16_t* gb = Bt + (long long)(n0 + srow) * ldb + scol;
  char* lA = (char*)(&As[srow][0]) + (lane & 7) * 16;
  char* lB = (char*)(&Bs[srow][0]) + (lane & 7) * 16;

  f32x4 acc[4][4] = {};

#pragma unroll
  for (int kt = 0; kt < 4; kt++) {
    const int ko = kt * 64;
#pragma unroll
    for (int q = 0; q < 4; q++) {
      gload16(ga + (long long)q * 8 * lda + ko, lA + q * 1024);
      gload16(gb + (long long)q * 8 * ldb + ko, lB + q * 1024);
    }
    __syncthreads();
#pragma unroll
    for (int kk = 0; kk < 2; kk++) {
      bf16x8 af[4], bfv[4];
#pragma unroll
      for (int i = 0; i < 4; i++) af[i]  = *(const bf16x8*)&As[wm + i*16 + lr][kk*32 + lg*8];
#pragma unroll
      for (int j = 0; j < 4; j++) bfv[j] = *(const bf16x8*)&Bs[wn + j*16 + lr][kk*32 + lg*8];
#pragma unroll
      for (int i = 0; i < 4; i++)
#pragma unroll
        for (int j = 0; j < 4; j++)
          acc[i][j] = __builtin_amdgcn_mfma_f32_16x16x32_bf16(af[i], bfv[j], acc[i][j], 0, 0, 0);
    }
    if (kt < 3) __syncthreads();
  }

#pragma unroll
  for (int i = 0; i < 4; i++) {
#pragma unroll
    for (int j = 0; j < 4; j++) {
      const int col = n0 + wn + j * 16 + lr;
      const float bval = (FLAGS & GF_BIAS) ? bias[col] : 0.f;
#pragma unroll
      for (int e = 0; e < 4; e++) {
        const int row = m0 + wm + i * 16 + lg * 4 + e;
        float v = acc[i][j][e] + bval;
        if (FLAGS & GF_RES) v += (float)res[(long long)row * ldr + col];
        if (FLAGS & GF_GELU) v = gelu_exact(v);
        const long long ci = (long long)row * ldc + col;
        if (FLAGS & GF_F32OUT) ((float*)Cv)[ci] = v;
        else                   ((bf16_t*)Cv)[ci] = (bf16_t)v;
      }
    }
  }
}

// ---------------- bf16 MFMA GEMM: 64x64 tile, 4 waves, BK=64 ----------------
// 4x the blocks of the 128-tile for small-N GEMMs (occupancy-starved at 1/CU).
template<int FLAGS>
__global__ __launch_bounds__(256)
void gemm64(const bf16_t* __restrict__ A, const bf16_t* __restrict__ Bt,
            void* __restrict__ Cv, const float* __restrict__ bias,
            const bf16_t* __restrict__ res,
            int lda, int ldb, int ldc, int ldr)
{
  __shared__ __align__(16) bf16_t As[64][64];
  __shared__ __align__(16) bf16_t Bs[64][64];
  const int m0 = blockIdx.x * 64, n0 = blockIdx.y * 64;
  const int tid = threadIdx.x, lane = tid & 63, wave = tid >> 6;
  const int wm = (wave >> 1) * 32, wn = (wave & 1) * 32;
  const int lr = lane & 15, lg = lane >> 4;

  const int srow = tid >> 3;            // 0..31 (two 32-row rounds)
  const int scol = (tid & 7) * 8;
  const bf16_t* ga = A  + (long long)(m0 + srow) * lda + scol;
  const bf16_t* gb = Bt + (long long)(n0 + srow) * ldb + scol;
  char* lA = (char*)As + tid * 16;
  char* lB = (char*)Bs + tid * 16;

  f32x4 acc[2][2] = {};

#pragma unroll
  for (int kt = 0; kt < 4; kt++) {
    const int ko = kt * 64;
    gload16(ga + ko, lA);
    gload16(ga + 32LL * lda + ko, lA + 4096);
    gload16(gb + ko, lB);
    gload16(gb + 32LL * ldb + ko, lB + 4096);
    __syncthreads();
#pragma unroll
    for (int kk = 0; kk < 2; kk++) {
      bf16x8 af[2], bfv[2];
#pragma unroll
      for (int i = 0; i < 2; i++) af[i]  = *(const bf16x8*)&As[wm + i*16 + lr][kk*32 + lg*8];
#pragma unroll
      for (int j = 0; j < 2; j++) bfv[j] = *(const bf16x8*)&Bs[wn + j*16 + lr][kk*32 + lg*8];
#pragma unroll
      for (int i = 0; i < 2; i++)
#pragma unroll
        for (int j = 0; j < 2; j++)
          acc[i][j] = __builtin_amdgcn_mfma_f32_16x16x32_bf16(af[i], bfv[j], acc[i][j], 0, 0, 0);
    }
    if (kt < 3) __syncthreads();
  }

#pragma unroll
  for (int i = 0; i < 2; i++) {
#pragma unroll
    for (int j = 0; j < 2; j++) {
      const int col = n0 + wn + j * 16 + lr;
      const float bval = (FLAGS & GF_BIAS) ? bias[col] : 0.f;
#pragma unroll
      for (int e = 0; e < 4; e++) {
        const int row = m0 + wm + i * 16 + lg * 4 + e;
        float v = acc[i][j][e] + bval;
        if (FLAGS & GF_RES) v += (float)res[(long long)row * ldr + col];
        if (FLAGS & GF_GELU) v = gelu_exact(v);
        const long long ci = (long long)row * ldc + col;
        if (FLAGS & GF_F32OUT) ((float*)Cv)[ci] = v;
        else                   ((bf16_t*)Cv)[ci] = (bf16_t)v;
      }
    }
  }
}

// ---------------- scores GEMM + fused per-tile top-8 ------------------------
// Q,K: [16][1024][768] bf16 (Q at col 0, K at col 256). For each 128x128
// causal tile: compute scaled+masked scores into padded LDS, then 2 threads
// per row extract that row's top-8 of this tile -> CAND[b][row][jt][16].
__global__ __launch_bounds__(256)
void gemm_topk(const bf16_t* __restrict__ Qb, const bf16_t* __restrict__ Kb,
               float2* __restrict__ CAND, float scale)
{
  __shared__ __align__(16) char smem[128 * 129 * 4];
  bf16_t (*As)[64] = (bf16_t(*)[64])smem;
  bf16_t (*Bs)[64] = (bf16_t(*)[64])(smem + 16384);
  float* sm = (float*)smem;

  const int z = blockIdx.z;
  const int m0 = blockIdx.x * 128, n0 = blockIdx.y * 128;
  if (n0 > m0) return;  // tile fully above diagonal
  const bf16_t* A  = Qb + (long long)z * (1024LL * 768);
  const bf16_t* Bt = Kb + (long long)z * (1024LL * 768);
  const int tid = threadIdx.x, lane = tid & 63, wave = tid >> 6;
  const int wm = (wave >> 1) << 6, wn = (wave & 1) << 6;
  const int lr = lane & 15, lg = lane >> 4;

  const int srow = wave * 32 + (lane >> 3);
  const int scol = (lane & 7) * 8;
  const bf16_t* ga = A  + (long long)(m0 + srow) * 768 + scol;
  const bf16_t* gb = Bt + (long long)(n0 + srow) * 768 + scol;
  char* lA = (char*)(&As[srow][0]) + (lane & 7) * 16;
  char* lB = (char*)(&Bs[srow][0]) + (lane & 7) * 16;

  f32x4 acc[4][4] = {};

#pragma unroll
  for (int kt = 0; kt < 4; kt++) {
    const int ko = kt * 64;
#pragma unroll
    for (int q = 0; q < 4; q++) {
      gload16(ga + (long long)q * 8 * 768 + ko, lA + q * 1024);
      gload16(gb + (long long)q * 8 * 768 + ko, lB + q * 1024);
    }
    __syncthreads();
#pragma unroll
    for (int kk = 0; kk < 2; kk++) {
      bf16x8 af[4], bfv[4];
#pragma unroll
      for (int i = 0; i < 4; i++) af[i]  = *(const bf16x8*)&As[wm + i*16 + lr][kk*32 + lg*8];
#pragma unroll
      for (int j = 0; j < 4; j++) bfv[j] = *(const bf16x8*)&Bs[wn + j*16 + lr][kk*32 + lg*8];
#pragma unroll
      for (int i = 0; i < 4; i++)
#pragma unroll
        for (int j = 0; j < 4; j++)
          acc[i][j] = __builtin_amdgcn_mfma_f32_16x16x32_bf16(af[i], bfv[j], acc[i][j], 0, 0, 0);
    }
    __syncthreads();  // also protects the sm overwrite below
  }

  // write scaled+masked scores to padded LDS (stride 129 f32)
#pragma unroll
  for (int i = 0; i < 4; i++) {
#pragma unroll
    for (int j = 0; j < 4; j++) {
      const int lcol = wn + j * 16 + lr;
#pragma unroll
      for (int e = 0; e < 4; e++) {
        const int lrow = wm + i * 16 + lg * 4 + e;
        float v = acc[i][j][e] * scale;
        if (n0 + lcol > m0 + lrow) v = -__builtin_inff();
        sm[lrow * 129 + lcol] = v;
      }
    }
  }
  __syncthreads();

  // per-thread top-8 over 64 columns (2 threads per row)
  const int row = tid >> 1, half = tid & 1;
  const float* rp = sm + row * 129 + half * 64;
  const int cbase = n0 + half * 64;
  float tv[8]; int ti[8];
#pragma unroll
  for (int j = 0; j < 8; j++) { tv[j] = -__builtin_inff(); ti[j] = 0x7fffffff; }
#pragma unroll 4
  for (int c = 0; c < 64; c++) {
    const float s = rp[c];
    const int m = cbase + c;
    if (s > tv[7] || (s == tv[7] && m < ti[7])) {
      tv[7] = s; ti[7] = m;
#pragma unroll
      for (int j = 7; j > 0; j--) {
        const bool sw = (tv[j] > tv[j-1]) || (tv[j] == tv[j-1] && ti[j] < ti[j-1]);
        if (sw) {
          const float tf = tv[j]; tv[j] = tv[j-1]; tv[j-1] = tf;
          const int   tt = ti[j]; ti[j] = ti[j-1]; ti[j-1] = tt;
        }
      }
    }
  }
  float2* cp = CAND + (((long long)z * 1024 + (m0 + row)) * 8 + (n0 >> 7)) * 16 + half * 8;
#pragma unroll
  for (int j = 0; j < 8; j++) {
    float2 pr; pr.x = tv[j]; pr.y = __int_as_float(ti[j]);
    cp[j] = pr;
  }
}

// ---------------- final top-8 merge + softmax + V gather --------------------
// one wave per row; <=128 candidates (2 per lane)
__global__ __launch_bounds__(256)
void k_sel8(const float2* __restrict__ CAND, const bf16_t* __restrict__ QKV,
            bf16_t* __restrict__ O) {
  const int n = blockIdx.x * 4 + (threadIdx.x >> 6);
  const int b = blockIdx.y;
  const int lane = threadIdx.x & 63;
  const int ntc = ((n >> 7) + 1) * 16;
  const float2* base = CAND + ((long long)(b * 1024 + n)) * 128;
  float v0 = -__builtin_inff(), v1 = -__builtin_inff();
  int i0 = 0x7fffffff, i1 = 0x7fffffff;
  if (lane < ntc)      { const float2 c = base[lane];      v0 = c.x; i0 = __float_as_int(c.y); }
  if (lane + 64 < ntc) { const float2 c = base[lane + 64]; v1 = c.x; i1 = __float_as_int(c.y); }
  if (v1 > v0 || (v1 == v0 && i1 < i0)) {
    const float tf = v0; v0 = v1; v1 = tf;
    const int   tt = i0; i0 = i1; i1 = tt;
  }
  float outv[8]; int outi[8];
#pragma unroll
  for (int r = 0; r < 8; r++) {
    float bv = v0; int bi = i0; int bl = lane;
#pragma unroll
    for (int off = 32; off; off >>= 1) {
      const float ov = __shfl_xor(bv, off, 64);
      const int   oi = __shfl_xor(bi, off, 64);
      const int   ol = __shfl_xor(bl, off, 64);
      if (ov > bv || (ov == bv && oi < bi)) { bv = ov; bi = oi; bl = ol; }
    }
    outv[r] = bv; outi[r] = bi;
    if (lane == bl) { v0 = v1; i0 = i1; v1 = -__builtin_inff(); i1 = 0x7fffffff; }
  }
  const float mx = outv[0];
  float w[8]; float den = 0.f;
#pragma unroll
  for (int j = 0; j < 8; j++) {
    w[j] = (outv[j] > -__builtin_inff()) ? expf(outv[j] - mx) : 0.f;
    den += w[j];
  }
  const float inv = 1.f / den;
  float a[4] = {0.f, 0.f, 0.f, 0.f};
#pragma unroll
  for (int j = 0; j < 8; j++) {
    if (outv[j] > -__builtin_inff()) {
      const bf16x4 vv = *(const bf16x4*)(QKV + ((long long)b * 1024 + outi[j]) * 768 + 512 + lane * 4);
      const float wj = w[j] * inv;
#pragma unroll
      for (int e = 0; e < 4; e++) a[e] = fmaf(wj, (float)vv[e], a[e]);
    }
  }
  bf16x4 o4;
#pragma unroll
  for (int e = 0; e < 4; e++) o4[e] = (bf16_t)a[e];
  *(bf16x4*)(O + ((long long)(b * 1024 + n)) * 256 + lane * 4) = o4;
}

// ---------------- prep: weight transposes (f32->bf16), xe, fused biases -----
struct TD { const float* src; bf16_t* dst; int N; int k0; int ld; };
struct PrepArgs {
  TD d[15];
  const float* emb; const float* pos; bf16_t* XE;
  const float* msg_b1; const float* upd_b1;
  const float* q_b; const float* k_b; const float* v_b;
  float* BIAS3; float* QKVB;
};

__global__ __launch_bounds__(256) void k_prep(PrepArgs pa) {
  const int y = blockIdx.y, x = blockIdx.x, d = threadIdx.x;
  if (y < 15) {
    TD t = pa.d[y];
    if (x >= t.N) return;
    t.dst[(long long)x * 256 + d] = (bf16_t)t.src[(long long)(t.k0 + d) * t.ld + x];
  } else if (y == 15) {
    const int p = x >> 8, v = x & 255;
    pa.XE[(long long)x * 256 + d] = (bf16_t)(pa.emb[v * 256 + d] + pa.pos[p * 256 + d]);
  } else {
    if      (x == 0) pa.BIAS3[d] = pa.msg_b1[d];
    else if (x == 1) pa.BIAS3[256 + d] = 0.f;
    else if (x == 2) pa.BIAS3[512 + d] = pa.upd_b1[d];
    else if (x == 3) pa.QKVB[d] = pa.q_b[d];
    else if (x == 4) pa.QKVB[256 + d] = pa.k_b[d];
    else if (x == 5) pa.QKVB[512 + d] = pa.v_b[d];
  }
}

// ---------------- GRU gate (bf16 gi table) -----------------------------------
__global__ __launch_bounds__(64)
void k_gru_gate(const int* __restrict__ x, const bf16_t* __restrict__ gitab,
                const bf16_t* __restrict__ GH, const float* __restrict__ bhh,
                bf16_t* __restrict__ H, bf16_t* __restrict__ LOC, int t)
{
  const int s = blockIdx.x, lane = threadIdx.x, d0 = lane * 4;
  const int v = x[s * 4 + t];
  const bf16_t* gi = gitab + (long long)(t * 256 + v) * 768;
  const bf16x4 g_r = *(const bf16x4*)(gi + d0);
  const bf16x4 g_z = *(const bf16x4*)(gi + 256 + d0);
  const bf16x4 g_n = *(const bf16x4*)(gi + 512 + d0);
  float hr[4], hz[4], hn[4], hp[4];
  if (t == 0) {
#pragma unroll
    for (int e = 0; e < 4; e++) {
      hr[e] = bhh[d0 + e]; hz[e] = bhh[256 + d0 + e]; hn[e] = bhh[512 + d0 + e];
      hp[e] = 0.f;
    }
  } else {
    const bf16_t* gh = GH + (long long)s * 768;
    const bf16x4 a = *(const bf16x4*)(gh + d0);
    const bf16x4 b4 = *(const bf16x4*)(gh + 256 + d0);
    const bf16x4 c4 = *(const bf16x4*)(gh + 512 + d0);
    const bf16x4 hv = *(const bf16x4*)(H + (long long)s * 256 + d0);
#pragma unroll
    for (int e = 0; e < 4; e++) { hr[e] = a[e]; hz[e] = b4[e]; hn[e] = c4[e]; hp[e] = hv[e]; }
  }
  bf16x4 ho;
#pragma unroll
  for (int e = 0; e < 4; e++) {
    const float r = sigm((float)g_r[e] + hr[e]);
    const float zz = sigm((float)g_z[e] + hz[e]);
    const float nn = tanhf((float)g_n[e] + r * hn[e]);
    ho[e] = (bf16_t)((1.f - zz) * nn + zz * hp[e]);
  }
  *(bf16x4*)(H + (long long)s * 256 + d0) = ho;
  *(bf16x4*)(LOC + ((long long)s * 4 + t) * 256 + d0) = ho;
}

// ---------------- LN (generic, 64 threads/row) ------------------------------
__global__ __launch_bounds__(64)
void k_ln(const bf16_t* __restrict__ X, const bf16_t* __restrict__ ADD, int addmode,
          bf16_t* __restrict__ OUT, const float* __restrict__ g,
          const float* __restrict__ b)
{
  const long long r = blockIdx.x;
  const int d0 = threadIdx.x * 4;
  const bf16x4 xv = *(const bf16x4*)(X + r * 256 + d0);
  float xf[4];
#pragma unroll
  for (int e = 0; e < 4; e++) xf[e] = (float)xv[e];
  if (addmode == 1) {
    const bf16x4 av = *(const bf16x4*)(ADD + r * 256 + d0);
#pragma unroll
    for (int e = 0; e < 4; e++) xf[e] += (float)av[e];
  } else if (addmode == 2) {
    const bf16x4 av = *(const bf16x4*)(ADD + (r >> 2) * 256 + d0);
#pragma unroll
    for (int e = 0; e < 4; e++) xf[e] += (float)av[e];
  }
  const float mean = wave_sum(xf[0] + xf[1] + xf[2] + xf[3]) * (1.f / 256.f);
  float q = 0.f;
#pragma unroll
  for (int e = 0; e < 4; e++) { const float dx = xf[e] - mean; q += dx * dx; }
  const float rstd = rsqrtf(wave_sum(q) * (1.f / 256.f) + 1e-5f);
  const float4 gv = *(const float4*)(g + d0);
  const float4 bv = *(const float4*)(b + d0);
  const float gg[4] = {gv.x, gv.y, gv.z, gv.w};
  const float bb[4] = {bv.x, bv.y, bv.z, bv.w};
  bf16x4 ov;
#pragma unroll
  for (int e = 0; e < 4; e++) ov[e] = (bf16_t)((xf[e] - mean) * rstd * gg[e] + bb[e]);
  *(bf16x4*)(OUT + r * 256 + d0) = ov;
}

// ---------------- fused patch-LN + mean over 4 rows -------------------------
__global__ __launch_bounds__(64)
void k_lnp4(bf16_t* __restrict__ LOC, bf16_t* __restrict__ SUMB,
            const float* __restrict__ g, const float* __restrict__ b)
{
  const long long s = blockIdx.x;
  const int d0 = threadIdx.x * 4;
  const float4 gv = *(const float4*)(g + d0);
  const float4 bv = *(const float4*)(b + d0);
  const float gg[4] = {gv.x, gv.y, gv.z, gv.w};
  const float bb[4] = {bv.x, bv.y, bv.z, bv.w};
  float accd[4] = {0.f, 0.f, 0.f, 0.f};
#pragma unroll
  for (int t = 0; t < 4; t++) {
    bf16_t* row = LOC + (s * 4 + t) * 256 + d0;
    const bf16x4 xv = *(const bf16x4*)row;
    float xf[4];
#pragma unroll
    for (int e = 0; e < 4; e++) xf[e] = (float)xv[e];
    const float mean = wave_sum(xf[0] + xf[1] + xf[2] + xf[3]) * (1.f / 256.f);
    float q = 0.f;
#pragma unroll
    for (int e = 0; e < 4; e++) { const float dx = xf[e] - mean; q += dx * dx; }
    const float rstd = rsqrtf(wave_sum(q) * (1.f / 256.f) + 1e-5f);
    bf16x4 ov;
#pragma unroll
    for (int e = 0; e < 4; e++) {
      const float y = (xf[e] - mean) * rstd * gg[e] + bb[e];
      ov[e] = (bf16_t)y;
      accd[e] += y;
    }
    *(bf16x4*)row = ov;
  }
  bf16x4 sv;
#pragma unroll
  for (int e = 0; e < 4; e++) sv[e] = (bf16_t)(accd[e] * 0.25f);
  *(bf16x4*)(SUMB + s * 256 + d0) = sv;
}

// ---------------- gelu-mix over window (reads fused A3) ---------------------
__global__ __launch_bounds__(64)
void k_gelumix(const bf16_t* __restrict__ A3, bf16_t* __restrict__ G)
{
  const long long s = blockIdx.x;
  const int n = (int)(s & 1023);
  const int d0 = threadIdx.x * 4;
  const bf16x4 av = *(const bf16x4*)(A3 + s * 768 + d0);
  float a[4];
#pragma unroll
  for (int e = 0; e < 4; e++) a[e] = (float)av[e];
  float acc[4] = {0.f, 0.f, 0.f, 0.f};
  const bf16_t* bbase = A3 + s * 768 + 256 + d0;
#pragma unroll
  for (int w = 0; w <= 4; w++) {
    if (n >= w) {
      const bf16x4 bn = *(const bf16x4*)(bbase - (long long)w * 768);
#pragma unroll
      for (int e = 0; e < 4; e++) acc[e] += gelu_exact(a[e] + (float)bn[e]);
    } else {
#pragma unroll
      for (int e = 0; e < 4; e++) acc[e] += gelu_exact(a[e]);
    }
  }
  bf16x4 ov;
#pragma unroll
  for (int e = 0; e < 4; e++) ov[e] = (bf16_t)(acc[e] * 0.2f);
  *(bf16x4*)(G + s * 256 + d0) = ov;
}

// ---------------- halting ----------------------------------------------------
__global__ __launch_bounds__(64)
void k_halt1(const bf16_t* __restrict__ Hm, float* __restrict__ PS) {
  const int c = blockIdx.x, b = blockIdx.y, d0 = threadIdx.x * 4;
  float acc[4] = {0.f, 0.f, 0.f, 0.f};
  const bf16_t* base = Hm + ((long long)b * 1024 + c * 32) * 256 + d0;
#pragma unroll 4
  for (int n = 0; n < 32; n++) {
    const bf16x4 hv = *(const bf16x4*)(base + (long long)n * 256);
#pragma unroll
    for (int e = 0; e < 4; e++) acc[e] += (float)hv[e];
  }
  float4 o4; o4.x = acc[0]; o4.y = acc[1]; o4.z = acc[2]; o4.w = acc[3];
  *(float4*)(PS + ((long long)b * 32 + c) * 256 + d0) = o4;
}

__global__ __launch_bounds__(64)
void k_halt2(const float* __restrict__ PS, const float* __restrict__ hw,
             const float* __restrict__ hb, float* __restrict__ HP) {
  const int b = blockIdx.x, d0 = threadIdx.x * 4;
  float acc[4] = {0.f, 0.f, 0.f, 0.f};
  for (int c = 0; c < 32; c++) {
    const float4 p4 = *(const float4*)(PS + ((long long)b * 32 + c) * 256 + d0);
    acc[0] += p4.x; acc[1] += p4.y; acc[2] += p4.z; acc[3] += p4.w;
  }
  const float4 w4 = *(const float4*)(hw + d0);
  float val = (acc[0] * w4.x + acc[1] * w4.y + acc[2] * w4.z + acc[3] * w4.w) * (1.f / 1024.f);
  val = wave_sum(val);
  if (threadIdx.x == 0) HP[b] = sigm(val + hb[0]);
}

__global__ void k_kl(const float* __restrict__ HP, float* __restrict__ out) {
  float s = 0.f;
  for (int b = 0; b < 16; b++) s += HP[b];
  const float hpm = s * (1.f / 16.f);
  const float l8 = logf(1e-8f);
  const float p0 = 0.2f, p1 = 0.16f, p2 = 0.128f, p3 = 0.1024f;
  const float kl = p0 * (logf(p0) - l8)
                 + p1 * (logf(p1) - l8)
                 + p2 * (logf(p2) - logf(hpm + 1e-8f))
                 + p3 * (logf(p3) - logf(1.f + 1e-8f));
  out[0] = kl * 0.25f;
}

__global__ __launch_bounds__(64)
void k_outmp(const bf16_t* __restrict__ Hm, const float* __restrict__ HP,
             bf16_t* __restrict__ O, int acc) {
  const long long s = blockIdx.x;
  const int d0 = threadIdx.x * 4;
  const int b = (int)(s >> 10);
  const float hp = HP[b];
  const bf16x4 hv = *(const bf16x4*)(Hm + s * 256 + d0);
  bf16x4 ov;
  if (acc) {
    const bf16x4 pv = *(const bf16x4*)(O + s * 256 + d0);
#pragma unroll
    for (int e = 0; e < 4; e++) ov[e] = (bf16_t)((float)pv[e] + (1.f - hp) * (float)hv[e]);
  } else {
#pragma unroll
    for (int e = 0; e < 4; e++) ov[e] = (bf16_t)(hp * (float)hv[e]);
  }
  *(bf16x4*)(O + s * 256 + d0) = ov;
}

// ---------------------------------------------------------------------------
extern "C" void kernel_launch(void* const* d_in, const int* in_sizes, int n_in,
                              void* d_out, int out_size, void* d_ws, size_t ws_size,
                              hipStream_t stream) {
  (void)in_sizes; (void)n_in; (void)ws_size;
  const int*   x      = (const int*)d_in[0];
  const float* emb    = (const float*)d_in[1];
  const float* pos    = (const float*)d_in[2];
  const float* wih    = (const float*)d_in[3];
  const float* whh    = (const float*)d_in[4];
  const float* bih    = (const float*)d_in[5];
  const float* bhh    = (const float*)d_in[6];
  const float* lnp_g  = (const float*)d_in[7];
  const float* lnp_b  = (const float*)d_in[8];
  const float* sum_w  = (const float*)d_in[9];
  const float* sum_b  = (const float*)d_in[10];
  const float* msg_w1 = (const float*)d_in[11];
  const float* msg_b1 = (const float*)d_in[12];
  const float* msg_w2 = (const float*)d_in[13];
  const float* msg_b2 = (const float*)d_in[14];
  const float* upd_w1 = (const float*)d_in[15];
  const float* upd_b1 = (const float*)d_in[16];
  const float* upd_w2 = (const float*)d_in[17];
  const float* upd_b2 = (const float*)d_in[18];
  const float* halt_w = (const float*)d_in[19];
  const float* halt_b = (const float*)d_in[20];
  const float* lnm_g  = (const float*)d_in[21];
  const float* lnm_b  = (const float*)d_in[22];
  const float* q_b    = (const float*)d_in[24];
  const float* k_b    = (const float*)d_in[26];
  const float* v_b    = (const float*)d_in[28];
  const float* o_b    = (const float*)d_in[30];
  const float* bc_b   = (const float*)d_in[32];
  const float* lnf_g  = (const float*)d_in[33];
  const float* lnf_b  = (const float*)d_in[34];

  char* base = (char*)d_ws;
  size_t off = 0;
  auto alloc = [&](size_t bytes) -> void* {
    void* p = (void*)(base + off);
    off += (bytes + 255) & ~(size_t)255;
    return p;
  };
  const size_t SL2 = 16384ull * 256 * 2;   // bf16 activation slab (8 MiB)
  bf16_t* WIHT  = (bf16_t*)alloc(768 * 256 * 2);
  bf16_t* WHHT  = (bf16_t*)alloc(768 * 256 * 2);
  bf16_t* SUMT  = (bf16_t*)alloc(256 * 256 * 2);
  bf16_t* MW    = (bf16_t*)alloc(768 * 256 * 2);   // [msgW1self; msgW1neigh; updW1h]
  bf16_t* W2T   = (bf16_t*)alloc(256 * 256 * 2);
  bf16_t* UW1MT = (bf16_t*)alloc(256 * 256 * 2);
  bf16_t* UW2T  = (bf16_t*)alloc(256 * 256 * 2);
  bf16_t* QKVW  = (bf16_t*)alloc(768 * 256 * 2);
  bf16_t* OT    = (bf16_t*)alloc(256 * 256 * 2);
  bf16_t* BCT   = (bf16_t*)alloc(256 * 256 * 2);
  bf16_t* HEADT = (bf16_t*)alloc(256 * 256 * 2);
  float*  BIAS3 = (float*)alloc(768 * 4);
  float*  QKVB  = (float*)alloc(768 * 4);
  bf16_t* XE    = (bf16_t*)alloc(1024ull * 256 * 2);
  bf16_t* GITAB = (bf16_t*)alloc(1024ull * 768 * 2);
  bf16_t* LOCb  = (bf16_t*)alloc(65536ull * 256 * 2);        // 32 MiB

  // --- 64 MiB overlay: GRU {GH,H} / phase-B {SUMB} / MP {A3} / CAND --------
  char*   SCR   = (char*)alloc(16ull * 1024 * 1024 * 4);     // 64 MiB
  float2* CAND  = (float2*)SCR;                              // 16.8 MiB (retrieval)
  bf16_t* GH    = (bf16_t*)SCR;                              // 24 MiB (GRU)
  bf16_t* H     = (bf16_t*)(SCR + 25165824);                 //  8 MiB (GRU)
  bf16_t* SUMB  = (bf16_t*)(SCR + 33554432);                 //  8 MiB (phase B)
  bf16_t* A3    = (bf16_t*)(SCR + 41943040);                 // 24 MiB (MP rounds)

  bf16_t* HMP   = (bf16_t*)alloc(SL2);
  bf16_t* G     = (bf16_t*)alloc(SL2);
  bf16_t* MSGS  = (bf16_t*)alloc(SL2);   // later BROAD
  bf16_t* UB    = (bf16_t*)alloc(SL2);   // later ATT
  bf16_t* U2B   = (bf16_t*)alloc(SL2);   // later COMB
  bf16_t* OUTMP = (bf16_t*)alloc(SL2);
  bf16_t* QKV   = (bf16_t*)alloc(16384ull * 768 * 2);        // 24 MiB
  float*  PS    = (float*)alloc(512ull * 256 * 4);
  float*  HP    = (float*)alloc(64);
  bf16_t* ATT   = UB;
  bf16_t* COMB  = U2B;
  bf16_t* BROAD = MSGS;
  float*  out   = (float*)d_out;
  float*  klout = out + (out_size - 1);

  // 1) prep: transposes + xe + fused biases
  PrepArgs pa;
  pa.d[0]  = { wih,                    WIHT,            768, 0,   768 };
  pa.d[1]  = { whh,                    WHHT,            768, 0,   768 };
  pa.d[2]  = { sum_w,                  SUMT,            256, 0,   256 };
  pa.d[3]  = { msg_w1,                 MW,              256, 0,   256 };
  pa.d[4]  = { msg_w1,                 MW + 256 * 256,  256, 256, 256 };
  pa.d[5]  = { upd_w1,                 MW + 512 * 256,  256, 0,   256 };
  pa.d[6]  = { msg_w2,                 W2T,             256, 0,   256 };
  pa.d[7]  = { upd_w1,                 UW1MT,           256, 256, 256 };
  pa.d[8]  = { upd_w2,                 UW2T,            256, 0,   256 };
  pa.d[9]  = { (const float*)d_in[23], QKVW,            256, 0,   256 };
  pa.d[10] = { (const float*)d_in[25], QKVW + 256*256,  256, 0,   256 };
  pa.d[11] = { (const float*)d_in[27], QKVW + 512*256,  256, 0,   256 };
  pa.d[12] = { (const float*)d_in[29], OT,              256, 0,   256 };
  pa.d[13] = { (const float*)d_in[31], BCT,             256, 0,   256 };
  pa.d[14] = { (const float*)d_in[35], HEADT,           256, 0,   256 };
  pa.emb = emb; pa.pos = pos; pa.XE = XE;
  pa.msg_b1 = msg_b1; pa.upd_b1 = upd_b1;
  pa.q_b = q_b; pa.k_b = k_b; pa.v_b = v_b;
  pa.BIAS3 = BIAS3; pa.QKVB = QKVB;
  k_prep<<<dim3(1024, 17), 256, 0, stream>>>(pa);

  // 2) GRU input table (bf16): gi = (emb+pos) @ wih + bih
  gemm64<GF_BIAS><<<dim3(16, 12), 256, 0, stream>>>(
      XE, WIHT, GITAB, bih, nullptr, 256, 256, 768, 0);

  // 3) GRU over 4 steps
  k_gru_gate<<<16384, 64, 0, stream>>>(x, GITAB, GH, bhh, H, LOCb, 0);
  for (int t = 1; t < 4; t++) {
    gemm64<GF_BIAS><<<dim3(256, 12), 256, 0, stream>>>(
        H, WHHT, GH, bhh, nullptr, 256, 256, 768, 0);
    k_gru_gate<<<16384, 64, 0, stream>>>(x, GITAB, GH, bhh, H, LOCb, t);
  }

  // 4) local = LN(gout) in place + patch means; summaries GEMM
  k_lnp4<<<16384, 64, 0, stream>>>(LOCb, SUMB, lnp_g, lnp_b);
  gemm64<GF_BIAS><<<dim3(256, 4), 256, 0, stream>>>(
      SUMB, SUMT, HMP, sum_b, nullptr, 256, 256, 256, 0);

  // 5) message-passing rounds
  for (int step = 0; step < 4; step++) {
    gemm64<GF_BIAS><<<dim3(256, 12), 256, 0, stream>>>(
        HMP, MW, A3, BIAS3, nullptr, 256, 256, 768, 0);
    k_gelumix<<<16384, 64, 0, stream>>>(A3, G);
    gemm64<GF_BIAS><<<dim3(256, 4), 256, 0, stream>>>(
        G, W2T, MSGS, msg_b2, nullptr, 256, 256, 256, 0);
    gemm64<GF_RES | GF_GELU><<<dim3(256, 4), 256, 0, stream>>>(
        MSGS, UW1MT, UB, nullptr, A3 + 512, 256, 256, 256, 768);
    gemm64<GF_BIAS><<<dim3(256, 4), 256, 0, stream>>>(
        UB, UW2T, U2B, upd_b2, nullptr, 256, 256, 256, 0);
    k_ln<<<16384, 64, 0, stream>>>(HMP, U2B, 1, HMP, lnm_g, lnm_b);
    if (step == 2) {
      k_halt1<<<dim3(32, 16), 64, 0, stream>>>(HMP, PS);
      k_halt2<<<16, 64, 0, stream>>>(PS, halt_w, halt_b, HP);
      k_kl<<<1, 1, 0, stream>>>(HP, klout);
      k_outmp<<<16384, 64, 0, stream>>>(HMP, HP, OUTMP, 0);
    } else if (step == 3) {
      k_outmp<<<16384, 64, 0, stream>>>(HMP, HP, OUTMP, 1);
    }
  }

  // 6) retrieval: QKV; fused scores+top8; merge/softmax/gather; out proj
  gemm64<GF_BIAS><<<dim3(256, 12), 256, 0, stream>>>(
      OUTMP, QKVW, QKV, QKVB, nullptr, 256, 256, 768, 0);
  gemm_topk<<<dim3(8, 8, 16), 256, 0, stream>>>(QKV, QKV + 256, CAND, 0.0625f);
  k_sel8<<<dim3(256, 16), 256, 0, stream>>>(CAND, QKV, ATT);
  gemm64<GF_BIAS | GF_RES><<<dim3(256, 4), 256, 0, stream>>>(
      ATT, OT, COMB, o_b, OUTMP, 256, 256, 256, 256);
  gemm64<GF_BIAS><<<dim3(256, 4), 256, 0, stream>>>(
      COMB, BCT, BROAD, bc_b, nullptr, 256, 256, 256, 0);

  // 7) final = LN(local + broad) in place; logits = final @ head_w (f32 out)
  k_ln<<<65536, 64, 0, stream>>>(LOCb, BROAD, 2, LOCb, lnf_g, lnf_b);
  gemm_bt<GF_F32OUT><<<dim3(512, 2), 256, 0, stream>>>(
      LOCb, HEADT, out, nullptr, nullptr, 256, 256, 256, 0);
}

// Round 5
// 491.582 us; speedup vs baseline: 1.2961x; 1.2961x over previous
//
#include <hip/hip_runtime.h>
#include <math.h>

// ---------------------------------------------------------------------------
// B=16, T=4096, D=256, V=256, PATCH=4, Np=1024, BN=16384
// All GEMMs: C[M,N] = A[M,256] @ Bt[N,256]^T (+epilogue), bf16 inputs, K=256.
// LDS tiles XOR-swizzled (T2): global source pre-swizzled (global_load_lds has
// a linear dest), fragment reads XOR the same key -> 16-way conflict fixed.
// ---------------------------------------------------------------------------

typedef __bf16 bf16_t;
typedef bf16_t bf16x8 __attribute__((ext_vector_type(8)));
typedef bf16_t bf16x4 __attribute__((ext_vector_type(4)));
typedef float f32x4 __attribute__((ext_vector_type(4)));

#define GF_BIAS 1
#define GF_GELU 4
#define GF_RES 8
#define GF_SCAUSAL 16
#define GF_F32OUT 32

__device__ __forceinline__ float gelu_exact(float x) {
  return 0.5f * x * (1.0f + erff(x * 0.7071067811865475f));
}

__device__ __forceinline__ float sigm(float x) { return 1.f / (1.f + expf(-x)); }

__device__ __forceinline__ float wave_sum(float v) {
#pragma unroll
  for (int o = 32; o; o >>= 1) v += __shfl_xor(v, o, 64);
  return v;
}

__device__ __forceinline__ void gload16(const void* g, void* l) {
  __builtin_amdgcn_global_load_lds(
      (const __attribute__((address_space(1))) void*)g,
      (__attribute__((address_space(3))) void*)l, 16, 0, 0);
}

// sortable u64 key: (order-preserving f32 map) << 32 | (0x7FFFFFFF - m)
// larger key == (larger score, then lower index). Unique per (s,m).
__device__ __forceinline__ unsigned long long skey(float s, int m) {
  unsigned u = __float_as_uint(s);
  u ^= (u & 0x80000000u) ? 0xFFFFFFFFu : 0x80000000u;
  return ((unsigned long long)u << 32) | (unsigned)(0x7FFFFFFF - m);
}

// ---------------- bf16 MFMA GEMM: 128x128 tile, 4 waves, BK=64, swizzled ----
template<int FLAGS>
__global__ __launch_bounds__(256)
void gemm_bt(const bf16_t* __restrict__ A, const bf16_t* __restrict__ Bt,
             void* __restrict__ Cv, const float* __restrict__ bias,
             const bf16_t* __restrict__ res,
             int lda, int ldb, int ldc, int ldr,
             long long sA, long long sB, long long sC, float scale)
{
  __shared__ __align__(16) bf16_t As[128][64];
  __shared__ __align__(16) bf16_t Bs[128][64];
  const int z = blockIdx.z;
  A  += (long long)z * sA;
  Bt += (long long)z * sB;
  const int m0 = blockIdx.x * 128, n0 = blockIdx.y * 128;
  if ((FLAGS & GF_SCAUSAL) && n0 > m0) return;  // tile fully above diagonal
  const int tid = threadIdx.x, lane = tid & 63, wave = tid >> 6;
  const int wm = (wave >> 1) << 6, wn = (wave & 1) << 6;
  const int lr = lane & 15, lg = lane >> 4;
  const int cx = lane & 7;                      // = row&7 in fragment reads

  // staging: linear LDS dest (wave base + lane*16); swizzle the global source
  const int srow = wave * 32 + (lane >> 3);
  const int scol = (((lane & 7) ^ ((lane >> 3) & 7)) * 8);
  const bf16_t* ga = A  + (long long)(m0 + srow) * lda + scol;
  const bf16_t* gb = Bt + (long long)(n0 + srow) * ldb + scol;
  char* lA = (char*)(&As[srow][0]) + (lane & 7) * 16;
  char* lB = (char*)(&Bs[srow][0]) + (lane & 7) * 16;

  f32x4 acc[4][4] = {};

#pragma unroll
  for (int kt = 0; kt < 4; kt++) {
    const int ko = kt * 64;
#pragma unroll
    for (int q = 0; q < 4; q++) {
      gload16(ga + (long long)q * 8 * lda + ko, lA + q * 1024);
      gload16(gb + (long long)q * 8 * ldb + ko, lB + q * 1024);
    }
    __syncthreads();
#pragma unroll
    for (int kk = 0; kk < 2; kk++) {
      const int co = ((kk * 4 + lg) ^ cx) << 4;  // swizzled 16B chunk offset
      bf16x8 af[4], bfv[4];
#pragma unroll
      for (int i = 0; i < 4; i++)
        af[i]  = *(const bf16x8*)((char*)As + (wm + i * 16 + lr) * 128 + co);
#pragma unroll
      for (int j = 0; j < 4; j++)
        bfv[j] = *(const bf16x8*)((char*)Bs + (wn + j * 16 + lr) * 128 + co);
#pragma unroll
      for (int i = 0; i < 4; i++)
#pragma unroll
        for (int j = 0; j < 4; j++)
          acc[i][j] = __builtin_amdgcn_mfma_f32_16x16x32_bf16(af[i], bfv[j], acc[i][j], 0, 0, 0);
    }
    if (kt < 3) __syncthreads();
  }

#pragma unroll
  for (int i = 0; i < 4; i++) {
#pragma unroll
    for (int j = 0; j < 4; j++) {
      const int col = n0 + wn + j * 16 + lr;
      const float bval = (FLAGS & GF_BIAS) ? bias[col] : 0.f;
#pragma unroll
      for (int e = 0; e < 4; e++) {
        const int row = m0 + wm + i * 16 + lg * 4 + e;
        float v = acc[i][j][e];
        if (FLAGS & GF_SCAUSAL) { v *= scale; if (col > row) v = -__builtin_inff(); }
        v += bval;
        if (FLAGS & GF_RES) v += (float)res[(long long)row * ldr + col];
        if (FLAGS & GF_GELU) v = gelu_exact(v);
        const long long ci = (long long)z * sC + (long long)row * ldc + col;
        if (FLAGS & GF_F32OUT) ((float*)Cv)[ci] = v;
        else                   ((bf16_t*)Cv)[ci] = (bf16_t)v;
      }
    }
  }
}

// ---------------- bf16 MFMA GEMM: 64x64 tile, 4 waves, BK=64, swizzled ------
template<int FLAGS>
__global__ __launch_bounds__(256)
void gemm64(const bf16_t* __restrict__ A, const bf16_t* __restrict__ Bt,
            void* __restrict__ Cv, const float* __restrict__ bias,
            const bf16_t* __restrict__ res,
            int lda, int ldb, int ldc, int ldr)
{
  __shared__ __align__(16) bf16_t As[64][64];
  __shared__ __align__(16) bf16_t Bs[64][64];
  const int m0 = blockIdx.x * 64, n0 = blockIdx.y * 64;
  const int tid = threadIdx.x, lane = tid & 63, wave = tid >> 6;
  const int wm = (wave >> 1) * 32, wn = (wave & 1) * 32;
  const int lr = lane & 15, lg = lane >> 4;
  const int cx = lane & 7;

  const int srow = tid >> 3;            // 0..31 (two 32-row rounds)
  const int scol = (((tid & 7) ^ (srow & 7)) * 8);   // pre-swizzled source
  const bf16_t* ga = A  + (long long)(m0 + srow) * lda + scol;
  const bf16_t* gb = Bt + (long long)(n0 + srow) * ldb + scol;
  char* lA = (char*)As + tid * 16;
  char* lB = (char*)Bs + tid * 16;

  f32x4 acc[2][2] = {};

#pragma unroll
  for (int kt = 0; kt < 4; kt++) {
    const int ko = kt * 64;
    gload16(ga + ko, lA);
    gload16(ga + 32LL * lda + ko, lA + 4096);
    gload16(gb + ko, lB);
    gload16(gb + 32LL * ldb + ko, lB + 4096);
    __syncthreads();
#pragma unroll
    for (int kk = 0; kk < 2; kk++) {
      const int co = ((kk * 4 + lg) ^ cx) << 4;
      bf16x8 af[2], bfv[2];
#pragma unroll
      for (int i = 0; i < 2; i++)
        af[i]  = *(const bf16x8*)((char*)As + (wm + i * 16 + lr) * 128 + co);
#pragma unroll
      for (int j = 0; j < 2; j++)
        bfv[j] = *(const bf16x8*)((char*)Bs + (wn + j * 16 + lr) * 128 + co);
#pragma unroll
      for (int i = 0; i < 2; i++)
#pragma unroll
        for (int j = 0; j < 2; j++)
          acc[i][j] = __builtin_amdgcn_mfma_f32_16x16x32_bf16(af[i], bfv[j], acc[i][j], 0, 0, 0);
    }
    if (kt < 3) __syncthreads();
  }

#pragma unroll
  for (int i = 0; i < 2; i++) {
#pragma unroll
    for (int j = 0; j < 2; j++) {
      const int col = n0 + wn + j * 16 + lr;
      const float bval = (FLAGS & GF_BIAS) ? bias[col] : 0.f;
#pragma unroll
      for (int e = 0; e < 4; e++) {
        const int row = m0 + wm + i * 16 + lg * 4 + e;
        float v = acc[i][j][e] + bval;
        if (FLAGS & GF_RES) v += (float)res[(long long)row * ldr + col];
        if (FLAGS & GF_GELU) v = gelu_exact(v);
        const long long ci = (long long)row * ldc + col;
        if (FLAGS & GF_F32OUT) ((float*)Cv)[ci] = v;
        else                   ((bf16_t*)Cv)[ci] = (bf16_t)v;
      }
    }
  }
}

// ---------------- prep: weight transposes (f32->bf16), xe, fused biases -----
struct TD { const float* src; bf16_t* dst; int N; int k0; int ld; };  // k0<0: direct copy
struct PrepArgs {
  TD d[16];
  const float* emb; const float* pos; bf16_t* XE;
  const float* msg_b1; const float* msg_b2; const float* upd_w1; const float* upd_b1;
  const float* q_b; const float* k_b; const float* v_b;
  float* BIAS3; float* QKVB;
};

__global__ __launch_bounds__(256) void k_prep(PrepArgs pa) {
  const int y = blockIdx.y, x = blockIdx.x, d = threadIdx.x;
  if (y < 16) {
    TD t = pa.d[y];
    if (x >= t.N) return;
    if (t.k0 < 0) t.dst[(long long)x * 256 + d] = (bf16_t)t.src[(long long)x * t.ld + d];
    else          t.dst[(long long)x * 256 + d] = (bf16_t)t.src[(long long)(t.k0 + d) * t.ld + x];
  } else if (y == 16) {
    const int p = x >> 8, v = x & 255;
    pa.XE[(long long)x * 256 + d] = (bf16_t)(pa.emb[v * 256 + d] + pa.pos[p * 256 + d]);
  } else {
    if      (x == 0) pa.BIAS3[d] = pa.msg_b1[d];
    else if (x == 1) pa.BIAS3[256 + d] = 0.f;
    else if (x == 2) {
      // c1[d] = upd_b1[d] + sum_k msg_b2[k] * upd_w1[256+k][d]
      float acc = pa.upd_b1[d];
      for (int k = 0; k < 256; k++) acc += pa.msg_b2[k] * pa.upd_w1[(long long)(256 + k) * 256 + d];
      pa.BIAS3[512 + d] = acc;
    }
    else if (x == 3) pa.QKVB[d] = pa.q_b[d];
    else if (x == 4) pa.QKVB[256 + d] = pa.k_b[d];
    else if (x == 5) pa.QKVB[512 + d] = pa.v_b[d];
  }
}

// ---------------- GRU gate (bf16 gi table) -----------------------------------
__global__ __launch_bounds__(64)
void k_gru_gate(const int* __restrict__ x, const bf16_t* __restrict__ gitab,
                const bf16_t* __restrict__ GH, const float* __restrict__ bhh,
                bf16_t* __restrict__ H, bf16_t* __restrict__ LOC, int t)
{
  const int s = blockIdx.x, lane = threadIdx.x, d0 = lane * 4;
  const int v = x[s * 4 + t];
  const bf16_t* gi = gitab + (long long)(t * 256 + v) * 768;
  const bf16x4 g_r = *(const bf16x4*)(gi + d0);
  const bf16x4 g_z = *(const bf16x4*)(gi + 256 + d0);
  const bf16x4 g_n = *(const bf16x4*)(gi + 512 + d0);
  float hr[4], hz[4], hn[4], hp[4];
  if (t == 0) {
#pragma unroll
    for (int e = 0; e < 4; e++) {
      hr[e] = bhh[d0 + e]; hz[e] = bhh[256 + d0 + e]; hn[e] = bhh[512 + d0 + e];
      hp[e] = 0.f;
    }
  } else {
    const bf16_t* gh = GH + (long long)s * 768;
    const bf16x4 a = *(const bf16x4*)(gh + d0);
    const bf16x4 b4 = *(const bf16x4*)(gh + 256 + d0);
    const bf16x4 c4 = *(const bf16x4*)(gh + 512 + d0);
    const bf16x4 hv = *(const bf16x4*)(H + (long long)s * 256 + d0);
#pragma unroll
    for (int e = 0; e < 4; e++) { hr[e] = a[e]; hz[e] = b4[e]; hn[e] = c4[e]; hp[e] = hv[e]; }
  }
  bf16x4 ho;
#pragma unroll
  for (int e = 0; e < 4; e++) {
    const float r = sigm((float)g_r[e] + hr[e]);
    const float zz = sigm((float)g_z[e] + hz[e]);
    const float nn = tanhf((float)g_n[e] + r * hn[e]);
    ho[e] = (bf16_t)((1.f - zz) * nn + zz * hp[e]);
  }
  *(bf16x4*)(H + (long long)s * 256 + d0) = ho;
  *(bf16x4*)(LOC + ((long long)s * 4 + t) * 256 + d0) = ho;
}

// ---------------- LN (generic, 64 threads/row) ------------------------------
__global__ __launch_bounds__(64)
void k_ln(const bf16_t* __restrict__ X, const bf16_t* __restrict__ ADD, int addmode,
          bf16_t* __restrict__ OUT, const float* __restrict__ g,
          const float* __restrict__ b)
{
  const long long r = blockIdx.x;
  const int d0 = threadIdx.x * 4;
  const bf16x4 xv = *(const bf16x4*)(X + r * 256 + d0);
  float xf[4];
#pragma unroll
  for (int e = 0; e < 4; e++) xf[e] = (float)xv[e];
  if (addmode == 1) {
    const bf16x4 av = *(const bf16x4*)(ADD + r * 256 + d0);
#pragma unroll
    for (int e = 0; e < 4; e++) xf[e] += (float)av[e];
  } else if (addmode == 2) {
    const bf16x4 av = *(const bf16x4*)(ADD + (r >> 2) * 256 + d0);
#pragma unroll
    for (int e = 0; e < 4; e++) xf[e] += (float)av[e];
  }
  const float mean = wave_sum(xf[0] + xf[1] + xf[2] + xf[3]) * (1.f / 256.f);
  float q = 0.f;
#pragma unroll
  for (int e = 0; e < 4; e++) { const float dx = xf[e] - mean; q += dx * dx; }
  const float rstd = rsqrtf(wave_sum(q) * (1.f / 256.f) + 1e-5f);
  const float4 gv = *(const float4*)(g + d0);
  const float4 bv = *(const float4*)(b + d0);
  const float gg[4] = {gv.x, gv.y, gv.z, gv.w};
  const float bb[4] = {bv.x, bv.y, bv.z, bv.w};
  bf16x4 ov;
#pragma unroll
  for (int e = 0; e < 4; e++) ov[e] = (bf16_t)((xf[e] - mean) * rstd * gg[e] + bb[e]);
  *(bf16x4*)(OUT + r * 256 + d0) = ov;
}

// ---------------- fused patch-LN + mean over 4 rows -------------------------
__global__ __launch_bounds__(64)
void k_lnp4(bf16_t* __restrict__ LOC, bf16_t* __restrict__ SUMB,
            const float* __restrict__ g, const float* __restrict__ b)
{
  const long long s = blockIdx.x;
  const int d0 = threadIdx.x * 4;
  const float4 gv = *(const float4*)(g + d0);
  const float4 bv = *(const float4*)(b + d0);
  const float gg[4] = {gv.x, gv.y, gv.z, gv.w};
  const float bb[4] = {bv.x, bv.y, bv.z, bv.w};
  float accd[4] = {0.f, 0.f, 0.f, 0.f};
#pragma unroll
  for (int t = 0; t < 4; t++) {
    bf16_t* row = LOC + (s * 4 + t) * 256 + d0;
    const bf16x4 xv = *(const bf16x4*)row;
    float xf[4];
#pragma unroll
    for (int e = 0; e < 4; e++) xf[e] = (float)xv[e];
    const float mean = wave_sum(xf[0] + xf[1] + xf[2] + xf[3]) * (1.f / 256.f);
    float q = 0.f;
#pragma unroll
    for (int e = 0; e < 4; e++) { const float dx = xf[e] - mean; q += dx * dx; }
    const float rstd = rsqrtf(wave_sum(q) * (1.f / 256.f) + 1e-5f);
    bf16x4 ov;
#pragma unroll
    for (int e = 0; e < 4; e++) {
      const float y = (xf[e] - mean) * rstd * gg[e] + bb[e];
      ov[e] = (bf16_t)y;
      accd[e] += y;
    }
    *(bf16x4*)row = ov;
  }
  bf16x4 sv;
#pragma unroll
  for (int e = 0; e < 4; e++) sv[e] = (bf16_t)(accd[e] * 0.25f);
  *(bf16x4*)(SUMB + s * 256 + d0) = sv;
}

// ---------------- gelu-mix over window (reads fused A3) ---------------------
__global__ __launch_bounds__(64)
void k_gelumix(const bf16_t* __restrict__ A3, bf16_t* __restrict__ G)
{
  const long long s = blockIdx.x;
  const int n = (int)(s & 1023);
  const int d0 = threadIdx.x * 4;
  const bf16x4 av = *(const bf16x4*)(A3 + s * 768 + d0);
  float a[4];
#pragma unroll
  for (int e = 0; e < 4; e++) a[e] = (float)av[e];
  float acc[4] = {0.f, 0.f, 0.f, 0.f};
  const bf16_t* bbase = A3 + s * 768 + 256 + d0;
#pragma unroll
  for (int w = 0; w <= 4; w++) {
    if (n >= w) {
      const bf16x4 bn = *(const bf16x4*)(bbase - (long long)w * 768);
#pragma unroll
      for (int e = 0; e < 4; e++) acc[e] += gelu_exact(a[e] + (float)bn[e]);
    } else {
#pragma unroll
      for (int e = 0; e < 4; e++) acc[e] += gelu_exact(a[e]);
    }
  }
  bf16x4 ov;
#pragma unroll
  for (int e = 0; e < 4; e++) ov[e] = (bf16_t)(acc[e] * 0.2f);
  *(bf16x4*)(G + s * 256 + d0) = ov;
}

// ---------------- halting ----------------------------------------------------
__global__ __launch_bounds__(64)
void k_halt1(const bf16_t* __restrict__ Hm, float* __restrict__ PS) {
  const int c = blockIdx.x, b = blockIdx.y, d0 = threadIdx.x * 4;
  float acc[4] = {0.f, 0.f, 0.f, 0.f};
  const bf16_t* base = Hm + ((long long)b * 1024 + c * 32) * 256 + d0;
#pragma unroll 4
  for (int n = 0; n < 32; n++) {
    const bf16x4 hv = *(const bf16x4*)(base + (long long)n * 256);
#pragma unroll
    for (int e = 0; e < 4; e++) acc[e] += (float)hv[e];
  }
  float4 o4; o4.x = acc[0]; o4.y = acc[1]; o4.z = acc[2]; o4.w = acc[3];
  *(float4*)(PS + ((long long)b * 32 + c) * 256 + d0) = o4;
}

__global__ __launch_bounds__(64)
void k_halt2(const float* __restrict__ PS, const float* __restrict__ hw,
             const float* __restrict__ hb, float* __restrict__ HP) {
  const int b = blockIdx.x, d0 = threadIdx.x * 4;
  float acc[4] = {0.f, 0.f, 0.f, 0.f};
  for (int c = 0; c < 32; c++) {
    const float4 p4 = *(const float4*)(PS + ((long long)b * 32 + c) * 256 + d0);
    acc[0] += p4.x; acc[1] += p4.y; acc[2] += p4.z; acc[3] += p4.w;
  }
  const float4 w4 = *(const float4*)(hw + d0);
  float val = (acc[0] * w4.x + acc[1] * w4.y + acc[2] * w4.z + acc[3] * w4.w) * (1.f / 1024.f);
  val = wave_sum(val);
  if (threadIdx.x == 0) HP[b] = sigm(val + hb[0]);
}

__global__ void k_kl(const float* __restrict__ HP, float* __restrict__ out) {
  float s = 0.f;
  for (int b = 0; b < 16; b++) s += HP[b];
  const float hpm = s * (1.f / 16.f);
  const float l8 = logf(1e-8f);
  const float p0 = 0.2f, p1 = 0.16f, p2 = 0.128f, p3 = 0.1024f;
  const float kl = p0 * (logf(p0) - l8)
                 + p1 * (logf(p1) - l8)
                 + p2 * (logf(p2) - logf(hpm + 1e-8f))
                 + p3 * (logf(p3) - logf(1.f + 1e-8f));
  out[0] = kl * 0.25f;
}

__global__ __launch_bounds__(64)
void k_outmp(const bf16_t* __restrict__ Hm, const float* __restrict__ HP,
             bf16_t* __restrict__ O, int acc) {
  const long long s = blockIdx.x;
  const int d0 = threadIdx.x * 4;
  const int b = (int)(s >> 10);
  const float hp = HP[b];
  const bf16x4 hv = *(const bf16x4*)(Hm + s * 256 + d0);
  bf16x4 ov;
  if (acc) {
    const bf16x4 pv = *(const bf16x4*)(O + s * 256 + d0);
#pragma unroll
    for (int e = 0; e < 4; e++) ov[e] = (bf16_t)((float)pv[e] + (1.f - hp) * (float)hv[e]);
  } else {
#pragma unroll
    for (int e = 0; e < 4; e++) ov[e] = (bf16_t)(hp * (float)hv[e]);
  }
  *(bf16x4*)(O + s * 256 + d0) = ov;
}

// ---------------- top-8 causal sparse attention (u64 keys, wave per row) ----
__global__ __launch_bounds__(256)
void k_topk(const float* __restrict__ S, const bf16_t* __restrict__ QKV,
            bf16_t* __restrict__ O) {
  const int n = blockIdx.x * 4 + (threadIdx.x >> 6);
  const int b = blockIdx.y;
  const int lane = threadIdx.x & 63;
  const float* srow = S + ((long long)(b * 1024 + n)) * 1024;
  unsigned long long kv[8] = {0, 0, 0, 0, 0, 0, 0, 0};
  for (int mb = lane * 4; mb <= n; mb += 256) {
    const float4 s4 = *(const float4*)(srow + mb);
    const float sv[4] = {s4.x, s4.y, s4.z, s4.w};
#pragma unroll
    for (int jj = 0; jj < 4; jj++) {
      const int m = mb + jj;
      if (m <= n) {
        const unsigned long long k = skey(sv[jj], m);
        if (k > kv[7]) {
          kv[7] = k;
#pragma unroll
          for (int j = 7; j > 0; j--) {
            if (kv[j] > kv[j-1]) {
              const unsigned long long t = kv[j]; kv[j] = kv[j-1]; kv[j-1] = t;
            }
          }
        }
      }
    }
  }
  // 8 rounds of wave-wide u64 max; winner lane pops its list head
  float wv[8]; int wi[8];
#pragma unroll
  for (int r = 0; r < 8; r++) {
    unsigned long long mk = kv[0];
#pragma unroll
    for (int off = 32; off; off >>= 1) {
      const unsigned long long ok = __shfl_xor(mk, off, 64);
      if (ok > mk) mk = ok;
    }
    if (mk != 0ull) {
      unsigned hi = (unsigned)(mk >> 32);
      hi ^= (hi & 0x80000000u) ? 0x80000000u : 0xFFFFFFFFu;
      wv[r] = __uint_as_float(hi);
      wi[r] = 0x7FFFFFFF - (int)(unsigned)(mk & 0xFFFFFFFFu);
    } else {
      wv[r] = 0.f; wi[r] = -1;
    }
    if (kv[0] == mk && mk != 0ull) {
#pragma unroll
      for (int j = 0; j < 7; j++) kv[j] = kv[j + 1];
      kv[7] = 0ull;
    }
  }
  const float mx = wv[0];
  float w[8]; float den = 0.f;
#pragma unroll
  for (int j = 0; j < 8; j++) {
    w[j] = (wi[j] >= 0) ? expf(wv[j] - mx) : 0.f;
    den += w[j];
  }
  const float inv = 1.f / den;
  float a[4] = {0.f, 0.f, 0.f, 0.f};
#pragma unroll
  for (int j = 0; j < 8; j++) {
    if (wi[j] >= 0) {
      const bf16x4 vv = *(const bf16x4*)(QKV + ((long long)b * 1024 + wi[j]) * 768 + 512 + lane * 4);
      const float wj = w[j] * inv;
#pragma unroll
      for (int e = 0; e < 4; e++) a[e] = fmaf(wj, (float)vv[e], a[e]);
    }
  }
  bf16x4 o4;
#pragma unroll
  for (int e = 0; e < 4; e++) o4[e] = (bf16_t)a[e];
  *(bf16x4*)(O + ((long long)(b * 1024 + n)) * 256 + lane * 4) = o4;
}

// ---------------------------------------------------------------------------
extern "C" void kernel_launch(void* const* d_in, const int* in_sizes, int n_in,
                              void* d_out, int out_size, void* d_ws, size_t ws_size,
                              hipStream_t stream) {
  (void)in_sizes; (void)n_in; (void)ws_size;
  const int*   x      = (const int*)d_in[0];
  const float* emb    = (const float*)d_in[1];
  const float* pos    = (const float*)d_in[2];
  const float* wih    = (const float*)d_in[3];
  const float* whh    = (const float*)d_in[4];
  const float* bih    = (const float*)d_in[5];
  const float* bhh    = (const float*)d_in[6];
  const float* lnp_g  = (const float*)d_in[7];
  const float* lnp_b  = (const float*)d_in[8];
  const float* sum_w  = (const float*)d_in[9];
  const float* sum_b  = (const float*)d_in[10];
  const float* msg_w1 = (const float*)d_in[11];
  const float* msg_b1 = (const float*)d_in[12];
  const float* msg_w2 = (const float*)d_in[13];
  const float* msg_b2 = (const float*)d_in[14];
  const float* upd_w1 = (const float*)d_in[15];
  const float* upd_b1 = (const float*)d_in[16];
  const float* upd_w2 = (const float*)d_in[17];
  const float* upd_b2 = (const float*)d_in[18];
  const float* halt_w = (const float*)d_in[19];
  const float* halt_b = (const float*)d_in[20];
  const float* lnm_g  = (const float*)d_in[21];
  const float* lnm_b  = (const float*)d_in[22];
  const float* q_b    = (const float*)d_in[24];
  const float* k_b    = (const float*)d_in[26];
  const float* v_b    = (const float*)d_in[28];
  const float* o_b    = (const float*)d_in[30];
  const float* bc_b   = (const float*)d_in[32];
  const float* lnf_g  = (const float*)d_in[33];
  const float* lnf_b  = (const float*)d_in[34];

  char* base = (char*)d_ws;
  size_t off = 0;
  auto alloc = [&](size_t bytes) -> void* {
    void* p = (void*)(base + off);
    off += (bytes + 255) & ~(size_t)255;
    return p;
  };
  const size_t SL2 = 16384ull * 256 * 2;   // bf16 activation slab (8 MiB)
  bf16_t* WIHT  = (bf16_t*)alloc(768 * 256 * 2);
  bf16_t* WHHT  = (bf16_t*)alloc(768 * 256 * 2);
  bf16_t* SUMT  = (bf16_t*)alloc(256 * 256 * 2);
  bf16_t* MW    = (bf16_t*)alloc(768 * 256 * 2);   // [msgW1self; msgW1neigh; updW1h]
  bf16_t* W2T   = (bf16_t*)alloc(256 * 256 * 2);
  bf16_t* W2NT  = (bf16_t*)alloc(256 * 256 * 2);   // msg_w2 direct (row-major)
  bf16_t* UW1MT = (bf16_t*)alloc(256 * 256 * 2);
  bf16_t* UW2T  = (bf16_t*)alloc(256 * 256 * 2);
  bf16_t* WCB   = (bf16_t*)alloc(256 * 256 * 2);   // (msg_w2 @ uw1m) in Bt form
  bf16_t* QKVW  = (bf16_t*)alloc(768 * 256 * 2);
  bf16_t* OT    = (bf16_t*)alloc(256 * 256 * 2);
  bf16_t* BCT   = (bf16_t*)alloc(256 * 256 * 2);
  bf16_t* HEADT = (bf16_t*)alloc(256 * 256 * 2);
  float*  BIAS3 = (float*)alloc(768 * 4);
  float*  QKVB  = (float*)alloc(768 * 4);
  bf16_t* XE    = (bf16_t*)alloc(1024ull * 256 * 2);
  bf16_t* GITAB = (bf16_t*)alloc(1024ull * 768 * 2);
  bf16_t* LOCb  = (bf16_t*)alloc(65536ull * 256 * 2);        // 32 MiB

  // --- 64 MiB overlay: GRU {GH,H} / phase-B {SUMB} / MP {A3} / SCORES ------
  char*   SCR   = (char*)alloc(16ull * 1024 * 1024 * 4);     // 64 MiB
  float*  SCORES = (float*)SCR;                              // retrieval phase
  bf16_t* GH    = (bf16_t*)SCR;                              // 24 MiB (GRU)
  bf16_t* H     = (bf16_t*)(SCR + 25165824);                 //  8 MiB (GRU)
  bf16_t* SUMB  = (bf16_t*)(SCR + 33554432);                 //  8 MiB (phase B)
  bf16_t* A3    = (bf16_t*)(SCR + 41943040);                 // 24 MiB (MP rounds)

  bf16_t* HMP   = (bf16_t*)alloc(SL2);
  bf16_t* G     = (bf16_t*)alloc(SL2);
  bf16_t* BROAD = (bf16_t*)alloc(SL2);
  bf16_t* UB    = (bf16_t*)alloc(SL2);   // later ATT
  bf16_t* U2B   = (bf16_t*)alloc(SL2);   // later COMB
  bf16_t* OUTMP = (bf16_t*)alloc(SL2);
  bf16_t* QKV   = (bf16_t*)alloc(16384ull * 768 * 2);        // 24 MiB
  float*  PS    = (float*)alloc(512ull * 256 * 4);
  float*  HP    = (float*)alloc(64);
  bf16_t* ATT   = UB;
  bf16_t* COMB  = U2B;
  float*  out   = (float*)d_out;
  float*  klout = out + (out_size - 1);

  // 1) prep: transposes + xe + fused biases
  PrepArgs pa;
  pa.d[0]  = { wih,                    WIHT,            768, 0,   768 };
  pa.d[1]  = { whh,                    WHHT,            768, 0,   768 };
  pa.d[2]  = { sum_w,                  SUMT,            256, 0,   256 };
  pa.d[3]  = { msg_w1,                 MW,              256, 0,   256 };
  pa.d[4]  = { msg_w1,                 MW + 256 * 256,  256, 256, 256 };
  pa.d[5]  = { upd_w1,                 MW + 512 * 256,  256, 0,   256 };
  pa.d[6]  = { msg_w2,                 W2T,             256, 0,   256 };
  pa.d[7]  = { upd_w1,                 UW1MT,           256, 256, 256 };
  pa.d[8]  = { upd_w2,                 UW2T,            256, 0,   256 };
  pa.d[9]  = { (const float*)d_in[23], QKVW,            256, 0,   256 };
  pa.d[10] = { (const float*)d_in[25], QKVW + 256*256,  256, 0,   256 };
  pa.d[11] = { (const float*)d_in[27], QKVW + 512*256,  256, 0,   256 };
  pa.d[12] = { (const float*)d_in[29], OT,              256, 0,   256 };
  pa.d[13] = { (const float*)d_in[31], BCT,             256, 0,   256 };
  pa.d[14] = { (const float*)d_in[35], HEADT,           256, 0,   256 };
  pa.d[15] = { msg_w2,                 W2NT,            256, -1,  256 };
  pa.emb = emb; pa.pos = pos; pa.XE = XE;
  pa.msg_b1 = msg_b1; pa.msg_b2 = msg_b2; pa.upd_w1 = upd_w1; pa.upd_b1 = upd_b1;
  pa.q_b = q_b; pa.k_b = k_b; pa.v_b = v_b;
  pa.BIAS3 = BIAS3; pa.QKVB = QKVB;
  k_prep<<<dim3(1024, 18), 256, 0, stream>>>(pa);

  // 1b) WCB[j][i] = sum_k uw1m[k][j] * msg_w2[i][k]  (Bt form of msg_w2@uw1m)
  gemm64<0><<<dim3(4, 4), 256, 0, stream>>>(
      UW1MT, W2NT, WCB, nullptr, nullptr, 256, 256, 256, 0);

  // 2) GRU input table (bf16): gi = (emb+pos) @ wih + bih
  gemm64<GF_BIAS><<<dim3(16, 12), 256, 0, stream>>>(
      XE, WIHT, GITAB, bih, nullptr, 256, 256, 768, 0);

  // 3) GRU over 4 steps
  k_gru_gate<<<16384, 64, 0, stream>>>(x, GITAB, GH, bhh, H, LOCb, 0);
  for (int t = 1; t < 4; t++) {
    gemm64<GF_BIAS><<<dim3(256, 12), 256, 0, stream>>>(
        H, WHHT, GH, bhh, nullptr, 256, 256, 768, 0);
    k_gru_gate<<<16384, 64, 0, stream>>>(x, GITAB, GH, bhh, H, LOCb, t);
  }

  // 4) local = LN(gout) in place + patch means; summaries GEMM
  k_lnp4<<<16384, 64, 0, stream>>>(LOCb, SUMB, lnp_g, lnp_b);
  gemm64<GF_BIAS><<<dim3(256, 4), 256, 0, stream>>>(
      SUMB, SUMT, HMP, sum_b, nullptr, 256, 256, 256, 0);

  // 5) message-passing rounds (WC fusion: msgs GEMM folded into UB GEMM)
  for (int step = 0; step < 4; step++) {
    gemm64<GF_BIAS><<<dim3(256, 12), 256, 0, stream>>>(
        HMP, MW, A3, BIAS3, nullptr, 256, 256, 768, 0);
    k_gelumix<<<16384, 64, 0, stream>>>(A3, G);
    gemm64<GF_RES | GF_GELU><<<dim3(256, 4), 256, 0, stream>>>(
        G, WCB, UB, nullptr, A3 + 512, 256, 256, 256, 768);
    gemm64<GF_BIAS><<<dim3(256, 4), 256, 0, stream>>>(
        UB, UW2T, U2B, upd_b2, nullptr, 256, 256, 256, 0);
    k_ln<<<16384, 64, 0, stream>>>(HMP, U2B, 1, HMP, lnm_g, lnm_b);
    if (step == 2) {
      k_halt1<<<dim3(32, 16), 64, 0, stream>>>(HMP, PS);
      k_halt2<<<16, 64, 0, stream>>>(PS, halt_w, halt_b, HP);
      k_kl<<<1, 1, 0, stream>>>(HP, klout);
      k_outmp<<<16384, 64, 0, stream>>>(HMP, HP, OUTMP, 0);
    } else if (step == 3) {
      k_outmp<<<16384, 64, 0, stream>>>(HMP, HP, OUTMP, 1);
    }
  }

  // 6) retrieval: QKV; causal scores (f32); u64 top-8 + softmax + V gather
  gemm64<GF_BIAS><<<dim3(256, 12), 256, 0, stream>>>(
      OUTMP, QKVW, QKV, QKVB, nullptr, 256, 256, 768, 0);
  gemm_bt<GF_SCAUSAL | GF_F32OUT><<<dim3(8, 8, 16), 256, 0, stream>>>(
      QKV, QKV + 256, SCORES, nullptr, nullptr, 768, 768, 1024, 0,
      1024LL * 768, 1024LL * 768, 1024LL * 1024, 0.0625f);
  k_topk<<<dim3(256, 16), 256, 0, stream>>>(SCORES, QKV, ATT);
  gemm64<GF_BIAS | GF_RES><<<dim3(256, 4), 256, 0, stream>>>(
      ATT, OT, COMB, o_b, OUTMP, 256, 256, 256, 256);
  gemm64<GF_BIAS><<<dim3(256, 4), 256, 0, stream>>>(
      COMB, BCT, BROAD, bc_b, nullptr, 256, 256, 256, 0);

  // 7) final = LN(local + broad) in place; logits = final @ head_w (f32 out)
  k_ln<<<65536, 64, 0, stream>>>(LOCb, BROAD, 2, LOCb, lnf_g, lnf_b);
  gemm_bt<GF_F32OUT><<<dim3(512, 2, 1), 256, 0, stream>>>(
      LOCb, HEADT, out, nullptr, nullptr, 256, 256, 256, 0, 0, 0, 0, 1.f);
}

// Round 6
// 487.537 us; speedup vs baseline: 1.3069x; 1.0083x over previous
//
#include <hip/hip_runtime.h>
#include <math.h>

// ---------------------------------------------------------------------------
// B=16, T=4096, D=256, V=256, PATCH=4, Np=1024, BN=16384
// All GEMMs: C[M,N] = A[M,256] @ Bt[N,256]^T (+epilogue), bf16 inputs, K=256.
// LDS tiles XOR-swizzled (T2). Sparse top-8 attention fully fused (no scores
// buffer): swapped-operand QK^T makes each Q-row's scores lane-local.
// ---------------------------------------------------------------------------

typedef __bf16 bf16_t;
typedef bf16_t bf16x8 __attribute__((ext_vector_type(8)));
typedef bf16_t bf16x4 __attribute__((ext_vector_type(4)));
typedef float f32x4 __attribute__((ext_vector_type(4)));

#define GF_BIAS 1
#define GF_GELU 4
#define GF_RES 8
#define GF_F32OUT 32

__device__ __forceinline__ float gelu_exact(float x) {
  return 0.5f * x * (1.0f + erff(x * 0.7071067811865475f));
}

__device__ __forceinline__ float sigm(float x) { return 1.f / (1.f + expf(-x)); }

__device__ __forceinline__ float wave_sum(float v) {
#pragma unroll
  for (int o = 32; o; o >>= 1) v += __shfl_xor(v, o, 64);
  return v;
}

__device__ __forceinline__ void gload16(const void* g, void* l) {
  __builtin_amdgcn_global_load_lds(
      (const __attribute__((address_space(1))) void*)g,
      (__attribute__((address_space(3))) void*)l, 16, 0, 0);
}

// sortable u64 key: (order-preserving f32 map) << 32 | (0x7FFFFFFF - m)
// larger key == (larger score, then lower index). Key 0 == empty slot.
__device__ __forceinline__ unsigned long long skey(float s, int m) {
  unsigned u = __float_as_uint(s);
  u ^= (u & 0x80000000u) ? 0xFFFFFFFFu : 0x80000000u;
  return ((unsigned long long)u << 32) | (unsigned)(0x7FFFFFFF - m);
}

// ---------------- bf16 MFMA GEMM: 128x128 tile, 4 waves, BK=64, swizzled ----
template<int FLAGS>
__global__ __launch_bounds__(256)
void gemm_bt(const bf16_t* __restrict__ A, const bf16_t* __restrict__ Bt,
             void* __restrict__ Cv, const float* __restrict__ bias,
             const bf16_t* __restrict__ res,
             int lda, int ldb, int ldc, int ldr)
{
  __shared__ __align__(16) bf16_t As[128][64];
  __shared__ __align__(16) bf16_t Bs[128][64];
  const int m0 = blockIdx.x * 128, n0 = blockIdx.y * 128;
  const int tid = threadIdx.x, lane = tid & 63, wave = tid >> 6;
  const int wm = (wave >> 1) << 6, wn = (wave & 1) << 6;
  const int lr = lane & 15, lg = lane >> 4;
  const int cx = lane & 7;

  // staging: linear LDS dest (wave base + lane*16); swizzle the global source
  const int srow = wave * 32 + (lane >> 3);
  const int scol = (((lane & 7) ^ ((lane >> 3) & 7)) * 8);
  const bf16_t* ga = A  + (long long)(m0 + srow) * lda + scol;
  const bf16_t* gb = Bt + (long long)(n0 + srow) * ldb + scol;
  char* lA = (char*)(&As[srow][0]) + (lane & 7) * 16;
  char* lB = (char*)(&Bs[srow][0]) + (lane & 7) * 16;

  f32x4 acc[4][4] = {};

#pragma unroll
  for (int kt = 0; kt < 4; kt++) {
    const int ko = kt * 64;
#pragma unroll
    for (int q = 0; q < 4; q++) {
      gload16(ga + (long long)q * 8 * lda + ko, lA + q * 1024);
      gload16(gb + (long long)q * 8 * ldb + ko, lB + q * 1024);
    }
    __syncthreads();
#pragma unroll
    for (int kk = 0; kk < 2; kk++) {
      const int co = ((kk * 4 + lg) ^ cx) << 4;  // swizzled 16B chunk offset
      bf16x8 af[4], bfv[4];
#pragma unroll
      for (int i = 0; i < 4; i++)
        af[i]  = *(const bf16x8*)((char*)As + (wm + i * 16 + lr) * 128 + co);
#pragma unroll
      for (int j = 0; j < 4; j++)
        bfv[j] = *(const bf16x8*)((char*)Bs + (wn + j * 16 + lr) * 128 + co);
#pragma unroll
      for (int i = 0; i < 4; i++)
#pragma unroll
        for (int j = 0; j < 4; j++)
          acc[i][j] = __builtin_amdgcn_mfma_f32_16x16x32_bf16(af[i], bfv[j], acc[i][j], 0, 0, 0);
    }
    if (kt < 3) __syncthreads();
  }

#pragma unroll
  for (int i = 0; i < 4; i++) {
#pragma unroll
    for (int j = 0; j < 4; j++) {
      const int col = n0 + wn + j * 16 + lr;
      const float bval = (FLAGS & GF_BIAS) ? bias[col] : 0.f;
#pragma unroll
      for (int e = 0; e < 4; e++) {
        const int row = m0 + wm + i * 16 + lg * 4 + e;
        float v = acc[i][j][e] + bval;
        if (FLAGS & GF_RES) v += (float)res[(long long)row * ldr + col];
        if (FLAGS & GF_GELU) v = gelu_exact(v);
        const long long ci = (long long)row * ldc + col;
        if (FLAGS & GF_F32OUT) ((float*)Cv)[ci] = v;
        else                   ((bf16_t*)Cv)[ci] = (bf16_t)v;
      }
    }
  }
}

// ---------------- bf16 MFMA GEMM: 64x64 tile, 4 waves, BK=64, swizzled ------
template<int FLAGS>
__global__ __launch_bounds__(256)
void gemm64(const bf16_t* __restrict__ A, const bf16_t* __restrict__ Bt,
            void* __restrict__ Cv, const float* __restrict__ bias,
            const bf16_t* __restrict__ res,
            int lda, int ldb, int ldc, int ldr)
{
  __shared__ __align__(16) bf16_t As[64][64];
  __shared__ __align__(16) bf16_t Bs[64][64];
  const int m0 = blockIdx.x * 64, n0 = blockIdx.y * 64;
  const int tid = threadIdx.x, lane = tid & 63, wave = tid >> 6;
  const int wm = (wave >> 1) * 32, wn = (wave & 1) * 32;
  const int lr = lane & 15, lg = lane >> 4;
  const int cx = lane & 7;

  const int srow = tid >> 3;            // 0..31 (two 32-row rounds)
  const int scol = (((tid & 7) ^ (srow & 7)) * 8);   // pre-swizzled source
  const bf16_t* ga = A  + (long long)(m0 + srow) * lda + scol;
  const bf16_t* gb = Bt + (long long)(n0 + srow) * ldb + scol;
  char* lA = (char*)As + tid * 16;
  char* lB = (char*)Bs + tid * 16;

  f32x4 acc[2][2] = {};

#pragma unroll
  for (int kt = 0; kt < 4; kt++) {
    const int ko = kt * 64;
    gload16(ga + ko, lA);
    gload16(ga + 32LL * lda + ko, lA + 4096);
    gload16(gb + ko, lB);
    gload16(gb + 32LL * ldb + ko, lB + 4096);
    __syncthreads();
#pragma unroll
    for (int kk = 0; kk < 2; kk++) {
      const int co = ((kk * 4 + lg) ^ cx) << 4;
      bf16x8 af[2], bfv[2];
#pragma unroll
      for (int i = 0; i < 2; i++)
        af[i]  = *(const bf16x8*)((char*)As + (wm + i * 16 + lr) * 128 + co);
#pragma unroll
      for (int j = 0; j < 2; j++)
        bfv[j] = *(const bf16x8*)((char*)Bs + (wn + j * 16 + lr) * 128 + co);
#pragma unroll
      for (int i = 0; i < 2; i++)
#pragma unroll
        for (int j = 0; j < 2; j++)
          acc[i][j] = __builtin_amdgcn_mfma_f32_16x16x32_bf16(af[i], bfv[j], acc[i][j], 0, 0, 0);
    }
    if (kt < 3) __syncthreads();
  }

#pragma unroll
  for (int i = 0; i < 2; i++) {
#pragma unroll
    for (int j = 0; j < 2; j++) {
      const int col = n0 + wn + j * 16 + lr;
      const float bval = (FLAGS & GF_BIAS) ? bias[col] : 0.f;
#pragma unroll
      for (int e = 0; e < 4; e++) {
        const int row = m0 + wm + i * 16 + lg * 4 + e;
        float v = acc[i][j][e] + bval;
        if (FLAGS & GF_RES) v += (float)res[(long long)row * ldr + col];
        if (FLAGS & GF_GELU) v = gelu_exact(v);
        const long long ci = (long long)row * ldc + col;
        if (FLAGS & GF_F32OUT) ((float*)Cv)[ci] = v;
        else                   ((bf16_t*)Cv)[ci] = (bf16_t)v;
      }
    }
  }
}

// ---------------- fused sparse top-8 attention ------------------------------
// One wave per 16 Q-rows. Swapped QK^T: mfma(K_frag, Q_frag) -> lane holds
// scores for Q-row (lane&15), K-rows {kt*16 + (lane>>4)*4 + e}. Lane-local
// u64-key top-8 -> 4-lane merge (xor 16,32) -> softmax -> V gather where each
// lane covers 64 d-elems of its Q-row.
__global__ __launch_bounds__(64)
void k_fatopk(const bf16_t* __restrict__ QKV, bf16_t* __restrict__ O) {
  const int b = blockIdx.y;
  const int qw = (int)((blockIdx.x + ((blockIdx.y * 21) & 63)) & 63);  // load balance
  const int lane = threadIdx.x;
  const int lr = lane & 15, lg = lane >> 4;
  const bf16_t* Qp = QKV + (long long)b * (1024LL * 768);
  const bf16_t* Kp = Qp + 256;
  const bf16_t* Vp = Qp + 512;
  const int q0 = qw * 16;
  const int qrow = q0 + lr;

  // Q fragments hoisted to registers (32 VGPR)
  bf16x8 bq[8];
#pragma unroll
  for (int s = 0; s < 8; s++)
    bq[s] = *(const bf16x8*)(Qp + (long long)qrow * 768 + s * 32 + lg * 8);

  unsigned long long kv[8] = {0ull, 0ull, 0ull, 0ull, 0ull, 0ull, 0ull, 0ull};

#define INS8(KEY) {                                                     \
    const unsigned long long k_ = (KEY);                                \
    if (k_ > kv[7]) {                                                   \
      kv[7] = k_;                                                       \
      _Pragma("unroll")                                                 \
      for (int j_ = 7; j_ > 0; j_--)                                    \
        if (kv[j_] > kv[j_-1]) {                                        \
          const unsigned long long t_ = kv[j_];                         \
          kv[j_] = kv[j_-1]; kv[j_-1] = t_;                             \
        }                                                               \
    }                                                                   \
  }

  const int klim = qw + 1;  // 16-row K-tiles to scan (causal)
  for (int kt = 0; kt < klim; kt += 2) {
    const int kt2 = (kt + 1 < klim) ? kt + 1 : kt;   // clamped (dup, discarded)
    const bf16_t* ka = Kp + (long long)(kt  * 16 + lr) * 768 + lg * 8;
    const bf16_t* kb = Kp + (long long)(kt2 * 16 + lr) * 768 + lg * 8;
    bf16x8 afA[8], afB[8];
#pragma unroll
    for (int s = 0; s < 8; s++) afA[s] = *(const bf16x8*)(ka + s * 32);
#pragma unroll
    for (int s = 0; s < 8; s++) afB[s] = *(const bf16x8*)(kb + s * 32);
    f32x4 a0 = {}, a1 = {};
#pragma unroll
    for (int s = 0; s < 8; s += 2) {
      a0 = __builtin_amdgcn_mfma_f32_16x16x32_bf16(afA[s],     bq[s],     a0, 0, 0, 0);
      a1 = __builtin_amdgcn_mfma_f32_16x16x32_bf16(afA[s + 1], bq[s + 1], a1, 0, 0, 0);
    }
#pragma unroll
    for (int e = 0; e < 4; e++) {
      const int m = kt * 16 + lg * 4 + e;
      if (m <= qrow) INS8(skey((a0[e] + a1[e]) * 0.0625f, m));
    }
    if (kt2 != kt) {
      f32x4 b0 = {}, b1 = {};
#pragma unroll
      for (int s = 0; s < 8; s += 2) {
        b0 = __builtin_amdgcn_mfma_f32_16x16x32_bf16(afB[s],     bq[s],     b0, 0, 0, 0);
        b1 = __builtin_amdgcn_mfma_f32_16x16x32_bf16(afB[s + 1], bq[s + 1], b1, 0, 0, 0);
      }
#pragma unroll
      for (int e = 0; e < 4; e++) {
        const int m = kt2 * 16 + lg * 4 + e;
        if (m <= qrow) INS8(skey((b0[e] + b1[e]) * 0.0625f, m));
      }
    }
  }
#undef INS8

  // merge top-8 across the 4 lanes sharing lr (xor 16, 32)
  float wv[8]; int wi[8];
#pragma unroll
  for (int r = 0; r < 8; r++) {
    unsigned long long mk = kv[0];
    unsigned long long ok = __shfl_xor(mk, 16, 64); if (ok > mk) mk = ok;
    ok = __shfl_xor(mk, 32, 64); if (ok > mk) mk = ok;
    if (mk != 0ull) {
      unsigned hi = (unsigned)(mk >> 32);
      hi ^= (hi & 0x80000000u) ? 0x80000000u : 0xFFFFFFFFu;
      wv[r] = __uint_as_float(hi);
      wi[r] = 0x7FFFFFFF - (int)(unsigned)(mk & 0xFFFFFFFFu);
    } else {
      wv[r] = 0.f; wi[r] = -1;
    }
    if (kv[0] == mk && mk != 0ull) {
#pragma unroll
      for (int j = 0; j < 7; j++) kv[j] = kv[j + 1];
      kv[7] = 0ull;
    }
  }

  // softmax over selected
  const float mx = wv[0];
  float w8[8]; float den = 0.f;
#pragma unroll
  for (int j = 0; j < 8; j++) {
    w8[j] = (wi[j] >= 0) ? expf(wv[j] - mx) : 0.f;
    den += w8[j];
  }
  const float inv = 1.f / den;

  // V gather: lane covers d in [lg*64, lg*64+64)
  f32x4 av[16] = {};
#pragma unroll
  for (int j = 0; j < 8; j++) {
    if (wi[j] >= 0) {
      const float wj = w8[j] * inv;
      const bf16_t* vr = Vp + (long long)wi[j] * 768 + lg * 64;
#pragma unroll
      for (int c = 0; c < 8; c++) {
        const bf16x8 vv = *(const bf16x8*)(vr + c * 8);
#pragma unroll
        for (int e = 0; e < 4; e++) {
          av[2 * c][e]     = fmaf(wj, (float)vv[e],     av[2 * c][e]);
          av[2 * c + 1][e] = fmaf(wj, (float)vv[4 + e], av[2 * c + 1][e]);
        }
      }
    }
  }
  bf16_t* op = O + ((long long)b * 1024 + qrow) * 256 + lg * 64;
#pragma unroll
  for (int c = 0; c < 8; c++) {
    bf16x8 ov;
#pragma unroll
    for (int e = 0; e < 4; e++) {
      ov[e]     = (bf16_t)av[2 * c][e];
      ov[4 + e] = (bf16_t)av[2 * c + 1][e];
    }
    *(bf16x8*)(op + c * 8) = ov;
  }
}

// ---------------- prep: weight transposes (f32->bf16), xe, fused biases -----
struct TD { const float* src; bf16_t* dst; int N; int k0; int ld; };  // k0<0: direct copy
struct PrepArgs {
  TD d[16];
  const float* emb; const float* pos; bf16_t* XE;
  const float* msg_b1; const float* msg_b2; const float* upd_w1; const float* upd_b1;
  const float* q_b; const float* k_b; const float* v_b;
  float* BIAS3; float* QKVB;
};

__global__ __launch_bounds__(256) void k_prep(PrepArgs pa) {
  const int y = blockIdx.y, x = blockIdx.x, d = threadIdx.x;
  if (y < 16) {
    TD t = pa.d[y];
    if (x >= t.N) return;
    if (t.k0 < 0) t.dst[(long long)x * 256 + d] = (bf16_t)t.src[(long long)x * t.ld + d];
    else          t.dst[(long long)x * 256 + d] = (bf16_t)t.src[(long long)(t.k0 + d) * t.ld + x];
  } else if (y == 16) {
    const int p = x >> 8, v = x & 255;
    pa.XE[(long long)x * 256 + d] = (bf16_t)(pa.emb[v * 256 + d] + pa.pos[p * 256 + d]);
  } else {
    if      (x == 0) pa.BIAS3[d] = pa.msg_b1[d];
    else if (x == 1) pa.BIAS3[256 + d] = 0.f;
    else if (x == 2) {
      // c1[d] = upd_b1[d] + sum_k msg_b2[k] * upd_w1[256+k][d]
      float acc = pa.upd_b1[d];
      for (int k = 0; k < 256; k++) acc += pa.msg_b2[k] * pa.upd_w1[(long long)(256 + k) * 256 + d];
      pa.BIAS3[512 + d] = acc;
    }
    else if (x == 3) pa.QKVB[d] = pa.q_b[d];
    else if (x == 4) pa.QKVB[256 + d] = pa.k_b[d];
    else if (x == 5) pa.QKVB[512 + d] = pa.v_b[d];
  }
}

// ---------------- GRU gate (bf16 gi table) -----------------------------------
__global__ __launch_bounds__(64)
void k_gru_gate(const int* __restrict__ x, const bf16_t* __restrict__ gitab,
                const bf16_t* __restrict__ GH, const float* __restrict__ bhh,
                bf16_t* __restrict__ H, bf16_t* __restrict__ LOC, int t)
{
  const int s = blockIdx.x, lane = threadIdx.x, d0 = lane * 4;
  const int v = x[s * 4 + t];
  const bf16_t* gi = gitab + (long long)(t * 256 + v) * 768;
  const bf16x4 g_r = *(const bf16x4*)(gi + d0);
  const bf16x4 g_z = *(const bf16x4*)(gi + 256 + d0);
  const bf16x4 g_n = *(const bf16x4*)(gi + 512 + d0);
  float hr[4], hz[4], hn[4], hp[4];
  if (t == 0) {
#pragma unroll
    for (int e = 0; e < 4; e++) {
      hr[e] = bhh[d0 + e]; hz[e] = bhh[256 + d0 + e]; hn[e] = bhh[512 + d0 + e];
      hp[e] = 0.f;
    }
  } else {
    const bf16_t* gh = GH + (long long)s * 768;
    const bf16x4 a = *(const bf16x4*)(gh + d0);
    const bf16x4 b4 = *(const bf16x4*)(gh + 256 + d0);
    const bf16x4 c4 = *(const bf16x4*)(gh + 512 + d0);
    const bf16x4 hv = *(const bf16x4*)(H + (long long)s * 256 + d0);
#pragma unroll
    for (int e = 0; e < 4; e++) { hr[e] = a[e]; hz[e] = b4[e]; hn[e] = c4[e]; hp[e] = hv[e]; }
  }
  bf16x4 ho;
#pragma unroll
  for (int e = 0; e < 4; e++) {
    const float r = sigm((float)g_r[e] + hr[e]);
    const float zz = sigm((float)g_z[e] + hz[e]);
    const float nn = tanhf((float)g_n[e] + r * hn[e]);
    ho[e] = (bf16_t)((1.f - zz) * nn + zz * hp[e]);
  }
  *(bf16x4*)(H + (long long)s * 256 + d0) = ho;
  *(bf16x4*)(LOC + ((long long)s * 4 + t) * 256 + d0) = ho;
}

// ---------------- LN (generic, 64 threads/row) ------------------------------
__global__ __launch_bounds__(64)
void k_ln(const bf16_t* __restrict__ X, const bf16_t* __restrict__ ADD, int addmode,
          bf16_t* __restrict__ OUT, const float* __restrict__ g,
          const float* __restrict__ b)
{
  const long long r = blockIdx.x;
  const int d0 = threadIdx.x * 4;
  const bf16x4 xv = *(const bf16x4*)(X + r * 256 + d0);
  float xf[4];
#pragma unroll
  for (int e = 0; e < 4; e++) xf[e] = (float)xv[e];
  if (addmode == 1) {
    const bf16x4 av = *(const bf16x4*)(ADD + r * 256 + d0);
#pragma unroll
    for (int e = 0; e < 4; e++) xf[e] += (float)av[e];
  } else if (addmode == 2) {
    const bf16x4 av = *(const bf16x4*)(ADD + (r >> 2) * 256 + d0);
#pragma unroll
    for (int e = 0; e < 4; e++) xf[e] += (float)av[e];
  }
  const float mean = wave_sum(xf[0] + xf[1] + xf[2] + xf[3]) * (1.f / 256.f);
  float q = 0.f;
#pragma unroll
  for (int e = 0; e < 4; e++) { const float dx = xf[e] - mean; q += dx * dx; }
  const float rstd = rsqrtf(wave_sum(q) * (1.f / 256.f) + 1e-5f);
  const float4 gv = *(const float4*)(g + d0);
  const float4 bv = *(const float4*)(b + d0);
  const float gg[4] = {gv.x, gv.y, gv.z, gv.w};
  const float bb[4] = {bv.x, bv.y, bv.z, bv.w};
  bf16x4 ov;
#pragma unroll
  for (int e = 0; e < 4; e++) ov[e] = (bf16_t)((xf[e] - mean) * rstd * gg[e] + bb[e]);
  *(bf16x4*)(OUT + r * 256 + d0) = ov;
}

// ---------------- fused patch-LN + mean over 4 rows -------------------------
__global__ __launch_bounds__(64)
void k_lnp4(bf16_t* __restrict__ LOC, bf16_t* __restrict__ SUMB,
            const float* __restrict__ g, const float* __restrict__ b)
{
  const long long s = blockIdx.x;
  const int d0 = threadIdx.x * 4;
  const float4 gv = *(const float4*)(g + d0);
  const float4 bv = *(const float4*)(b + d0);
  const float gg[4] = {gv.x, gv.y, gv.z, gv.w};
  const float bb[4] = {bv.x, bv.y, bv.z, bv.w};
  float accd[4] = {0.f, 0.f, 0.f, 0.f};
#pragma unroll
  for (int t = 0; t < 4; t++) {
    bf16_t* row = LOC + (s * 4 + t) * 256 + d0;
    const bf16x4 xv = *(const bf16x4*)row;
    float xf[4];
#pragma unroll
    for (int e = 0; e < 4; e++) xf[e] = (float)xv[e];
    const float mean = wave_sum(xf[0] + xf[1] + xf[2] + xf[3]) * (1.f / 256.f);
    float q = 0.f;
#pragma unroll
    for (int e = 0; e < 4; e++) { const float dx = xf[e] - mean; q += dx * dx; }
    const float rstd = rsqrtf(wave_sum(q) * (1.f / 256.f) + 1e-5f);
    bf16x4 ov;
#pragma unroll
    for (int e = 0; e < 4; e++) {
      const float y = (xf[e] - mean) * rstd * gg[e] + bb[e];
      ov[e] = (bf16_t)y;
      accd[e] += y;
    }
    *(bf16x4*)row = ov;
  }
  bf16x4 sv;
#pragma unroll
  for (int e = 0; e < 4; e++) sv[e] = (bf16_t)(accd[e] * 0.25f);
  *(bf16x4*)(SUMB + s * 256 + d0) = sv;
}

// ---------------- gelu-mix over window (reads fused A3) ---------------------
__global__ __launch_bounds__(64)
void k_gelumix(const bf16_t* __restrict__ A3, bf16_t* __restrict__ G)
{
  const long long s = blockIdx.x;
  const int n = (int)(s & 1023);
  const int d0 = threadIdx.x * 4;
  const bf16x4 av = *(const bf16x4*)(A3 + s * 768 + d0);
  float a[4];
#pragma unroll
  for (int e = 0; e < 4; e++) a[e] = (float)av[e];
  float acc[4] = {0.f, 0.f, 0.f, 0.f};
  const bf16_t* bbase = A3 + s * 768 + 256 + d0;
#pragma unroll
  for (int w = 0; w <= 4; w++) {
    if (n >= w) {
      const bf16x4 bn = *(const bf16x4*)(bbase - (long long)w * 768);
#pragma unroll
      for (int e = 0; e < 4; e++) acc[e] += gelu_exact(a[e] + (float)bn[e]);
    } else {
#pragma unroll
      for (int e = 0; e < 4; e++) acc[e] += gelu_exact(a[e]);
    }
  }
  bf16x4 ov;
#pragma unroll
  for (int e = 0; e < 4; e++) ov[e] = (bf16_t)(acc[e] * 0.2f);
  *(bf16x4*)(G + s * 256 + d0) = ov;
}

// ---------------- halting ----------------------------------------------------
__global__ __launch_bounds__(64)
void k_halt1(const bf16_t* __restrict__ Hm, float* __restrict__ PS) {
  const int c = blockIdx.x, b = blockIdx.y, d0 = threadIdx.x * 4;
  float acc[4] = {0.f, 0.f, 0.f, 0.f};
  const bf16_t* base = Hm + ((long long)b * 1024 + c * 32) * 256 + d0;
#pragma unroll 4
  for (int n = 0; n < 32; n++) {
    const bf16x4 hv = *(const bf16x4*)(base + (long long)n * 256);
#pragma unroll
    for (int e = 0; e < 4; e++) acc[e] += (float)hv[e];
  }
  float4 o4; o4.x = acc[0]; o4.y = acc[1]; o4.z = acc[2]; o4.w = acc[3];
  *(float4*)(PS + ((long long)b * 32 + c) * 256 + d0) = o4;
}

__global__ __launch_bounds__(64)
void k_halt2(const float* __restrict__ PS, const float* __restrict__ hw,
             const float* __restrict__ hb, float* __restrict__ HP) {
  const int b = blockIdx.x, d0 = threadIdx.x * 4;
  float acc[4] = {0.f, 0.f, 0.f, 0.f};
  for (int c = 0; c < 32; c++) {
    const float4 p4 = *(const float4*)(PS + ((long long)b * 32 + c) * 256 + d0);
    acc[0] += p4.x; acc[1] += p4.y; acc[2] += p4.z; acc[3] += p4.w;
  }
  const float4 w4 = *(const float4*)(hw + d0);
  float val = (acc[0] * w4.x + acc[1] * w4.y + acc[2] * w4.z + acc[3] * w4.w) * (1.f / 1024.f);
  val = wave_sum(val);
  if (threadIdx.x == 0) HP[b] = sigm(val + hb[0]);
}

__global__ void k_kl(const float* __restrict__ HP, float* __restrict__ out) {
  float s = 0.f;
  for (int b = 0; b < 16; b++) s += HP[b];
  const float hpm = s * (1.f / 16.f);
  const float l8 = logf(1e-8f);
  const float p0 = 0.2f, p1 = 0.16f, p2 = 0.128f, p3 = 0.1024f;
  const float kl = p0 * (logf(p0) - l8)
                 + p1 * (logf(p1) - l8)
                 + p2 * (logf(p2) - logf(hpm + 1e-8f))
                 + p3 * (logf(p3) - logf(1.f + 1e-8f));
  out[0] = kl * 0.25f;
}

__global__ __launch_bounds__(64)
void k_outmp(const bf16_t* __restrict__ Hm, const float* __restrict__ HP,
             bf16_t* __restrict__ O, int acc) {
  const long long s = blockIdx.x;
  const int d0 = threadIdx.x * 4;
  const int b = (int)(s >> 10);
  const float hp = HP[b];
  const bf16x4 hv = *(const bf16x4*)(Hm + s * 256 + d0);
  bf16x4 ov;
  if (acc) {
    const bf16x4 pv = *(const bf16x4*)(O + s * 256 + d0);
#pragma unroll
    for (int e = 0; e < 4; e++) ov[e] = (bf16_t)((float)pv[e] + (1.f - hp) * (float)hv[e]);
  } else {
#pragma unroll
    for (int e = 0; e < 4; e++) ov[e] = (bf16_t)(hp * (float)hv[e]);
  }
  *(bf16x4*)(O + s * 256 + d0) = ov;
}

// ---------------------------------------------------------------------------
extern "C" void kernel_launch(void* const* d_in, const int* in_sizes, int n_in,
                              void* d_out, int out_size, void* d_ws, size_t ws_size,
                              hipStream_t stream) {
  (void)in_sizes; (void)n_in; (void)ws_size;
  const int*   x      = (const int*)d_in[0];
  const float* emb    = (const float*)d_in[1];
  const float* pos    = (const float*)d_in[2];
  const float* wih    = (const float*)d_in[3];
  const float* whh    = (const float*)d_in[4];
  const float* bih    = (const float*)d_in[5];
  const float* bhh    = (const float*)d_in[6];
  const float* lnp_g  = (const float*)d_in[7];
  const float* lnp_b  = (const float*)d_in[8];
  const float* sum_w  = (const float*)d_in[9];
  const float* sum_b  = (const float*)d_in[10];
  const float* msg_w1 = (const float*)d_in[11];
  const float* msg_b1 = (const float*)d_in[12];
  const float* msg_w2 = (const float*)d_in[13];
  const float* msg_b2 = (const float*)d_in[14];
  const float* upd_w1 = (const float*)d_in[15];
  const float* upd_b1 = (const float*)d_in[16];
  const float* upd_w2 = (const float*)d_in[17];
  const float* upd_b2 = (const float*)d_in[18];
  const float* halt_w = (const float*)d_in[19];
  const float* halt_b = (const float*)d_in[20];
  const float* lnm_g  = (const float*)d_in[21];
  const float* lnm_b  = (const float*)d_in[22];
  const float* q_b    = (const float*)d_in[24];
  const float* k_b    = (const float*)d_in[26];
  const float* v_b    = (const float*)d_in[28];
  const float* o_b    = (const float*)d_in[30];
  const float* bc_b   = (const float*)d_in[32];
  const float* lnf_g  = (const float*)d_in[33];
  const float* lnf_b  = (const float*)d_in[34];

  char* base = (char*)d_ws;
  size_t off = 0;
  auto alloc = [&](size_t bytes) -> void* {
    void* p = (void*)(base + off);
    off += (bytes + 255) & ~(size_t)255;
    return p;
  };
  const size_t SL2 = 16384ull * 256 * 2;   // bf16 activation slab (8 MiB)
  bf16_t* WIHT  = (bf16_t*)alloc(768 * 256 * 2);
  bf16_t* WHHT  = (bf16_t*)alloc(768 * 256 * 2);
  bf16_t* SUMT  = (bf16_t*)alloc(256 * 256 * 2);
  bf16_t* MW    = (bf16_t*)alloc(768 * 256 * 2);   // [msgW1self; msgW1neigh; updW1h]
  bf16_t* W2T   = (bf16_t*)alloc(256 * 256 * 2);
  bf16_t* W2NT  = (bf16_t*)alloc(256 * 256 * 2);   // msg_w2 direct (row-major)
  bf16_t* UW1MT = (bf16_t*)alloc(256 * 256 * 2);
  bf16_t* UW2T  = (bf16_t*)alloc(256 * 256 * 2);
  bf16_t* WCB   = (bf16_t*)alloc(256 * 256 * 2);   // (msg_w2 @ uw1m) in Bt form
  bf16_t* QKVW  = (bf16_t*)alloc(768 * 256 * 2);
  bf16_t* OT    = (bf16_t*)alloc(256 * 256 * 2);
  bf16_t* BCT   = (bf16_t*)alloc(256 * 256 * 2);
  bf16_t* HEADT = (bf16_t*)alloc(256 * 256 * 2);
  float*  BIAS3 = (float*)alloc(768 * 4);
  float*  QKVB  = (float*)alloc(768 * 4);
  bf16_t* XE    = (bf16_t*)alloc(1024ull * 256 * 2);
  bf16_t* GITAB = (bf16_t*)alloc(1024ull * 768 * 2);
  bf16_t* LOCb  = (bf16_t*)alloc(65536ull * 256 * 2);        // 32 MiB

  // --- 64 MiB overlay: GRU {GH,H} / phase-B {SUMB} / MP {A3} ---------------
  char*   SCR   = (char*)alloc(16ull * 1024 * 1024 * 4);     // 64 MiB
  bf16_t* GH    = (bf16_t*)SCR;                              // 24 MiB (GRU)
  bf16_t* H     = (bf16_t*)(SCR + 25165824);                 //  8 MiB (GRU)
  bf16_t* SUMB  = (bf16_t*)(SCR + 33554432);                 //  8 MiB (phase B)
  bf16_t* A3    = (bf16_t*)(SCR + 41943040);                 // 24 MiB (MP rounds)

  bf16_t* HMP   = (bf16_t*)alloc(SL2);
  bf16_t* G     = (bf16_t*)alloc(SL2);
  bf16_t* BROAD = (bf16_t*)alloc(SL2);
  bf16_t* UB    = (bf16_t*)alloc(SL2);   // later ATT
  bf16_t* U2B   = (bf16_t*)alloc(SL2);   // later COMB
  bf16_t* OUTMP = (bf16_t*)alloc(SL2);
  bf16_t* QKV   = (bf16_t*)alloc(16384ull * 768 * 2);        // 24 MiB
  float*  PS    = (float*)alloc(512ull * 256 * 4);
  float*  HP    = (float*)alloc(64);
  bf16_t* ATT   = UB;
  bf16_t* COMB  = U2B;
  float*  out   = (float*)d_out;
  float*  klout = out + (out_size - 1);

  // 1) prep: transposes + xe + fused biases
  PrepArgs pa;
  pa.d[0]  = { wih,                    WIHT,            768, 0,   768 };
  pa.d[1]  = { whh,                    WHHT,            768, 0,   768 };
  pa.d[2]  = { sum_w,                  SUMT,            256, 0,   256 };
  pa.d[3]  = { msg_w1,                 MW,              256, 0,   256 };
  pa.d[4]  = { msg_w1,                 MW + 256 * 256,  256, 256, 256 };
  pa.d[5]  = { upd_w1,                 MW + 512 * 256,  256, 0,   256 };
  pa.d[6]  = { msg_w2,                 W2T,             256, 0,   256 };
  pa.d[7]  = { upd_w1,                 UW1MT,           256, 256, 256 };
  pa.d[8]  = { upd_w2,                 UW2T,            256, 0,   256 };
  pa.d[9]  = { (const float*)d_in[23], QKVW,            256, 0,   256 };
  pa.d[10] = { (const float*)d_in[25], QKVW + 256*256,  256, 0,   256 };
  pa.d[11] = { (const float*)d_in[27], QKVW + 512*256,  256, 0,   256 };
  pa.d[12] = { (const float*)d_in[29], OT,              256, 0,   256 };
  pa.d[13] = { (const float*)d_in[31], BCT,             256, 0,   256 };
  pa.d[14] = { (const float*)d_in[35], HEADT,           256, 0,   256 };
  pa.d[15] = { msg_w2,                 W2NT,            256, -1,  256 };
  pa.emb = emb; pa.pos = pos; pa.XE = XE;
  pa.msg_b1 = msg_b1; pa.msg_b2 = msg_b2; pa.upd_w1 = upd_w1; pa.upd_b1 = upd_b1;
  pa.q_b = q_b; pa.k_b = k_b; pa.v_b = v_b;
  pa.BIAS3 = BIAS3; pa.QKVB = QKVB;
  k_prep<<<dim3(1024, 18), 256, 0, stream>>>(pa);

  // 1b) WCB[j][i] = sum_k uw1m[k][j] * msg_w2[i][k]  (Bt form of msg_w2@uw1m)
  gemm64<0><<<dim3(4, 4), 256, 0, stream>>>(
      UW1MT, W2NT, WCB, nullptr, nullptr, 256, 256, 256, 0);

  // 2) GRU input table (bf16): gi = (emb+pos) @ wih + bih
  gemm64<GF_BIAS><<<dim3(16, 12), 256, 0, stream>>>(
      XE, WIHT, GITAB, bih, nullptr, 256, 256, 768, 0);

  // 3) GRU over 4 steps (128-tile for the N=768 GEMMs: 768 blocks = 3/CU)
  k_gru_gate<<<16384, 64, 0, stream>>>(x, GITAB, GH, bhh, H, LOCb, 0);
  for (int t = 1; t < 4; t++) {
    gemm_bt<GF_BIAS><<<dim3(128, 6), 256, 0, stream>>>(
        H, WHHT, GH, bhh, nullptr, 256, 256, 768, 0);
    k_gru_gate<<<16384, 64, 0, stream>>>(x, GITAB, GH, bhh, H, LOCb, t);
  }

  // 4) local = LN(gout) in place + patch means; summaries GEMM
  k_lnp4<<<16384, 64, 0, stream>>>(LOCb, SUMB, lnp_g, lnp_b);
  gemm64<GF_BIAS><<<dim3(256, 4), 256, 0, stream>>>(
      SUMB, SUMT, HMP, sum_b, nullptr, 256, 256, 256, 0);

  // 5) message-passing rounds (WC fusion: msgs GEMM folded into UB GEMM)
  for (int step = 0; step < 4; step++) {
    gemm_bt<GF_BIAS><<<dim3(128, 6), 256, 0, stream>>>(
        HMP, MW, A3, BIAS3, nullptr, 256, 256, 768, 0);
    k_gelumix<<<16384, 64, 0, stream>>>(A3, G);
    gemm64<GF_RES | GF_GELU><<<dim3(256, 4), 256, 0, stream>>>(
        G, WCB, UB, nullptr, A3 + 512, 256, 256, 256, 768);
    gemm64<GF_BIAS><<<dim3(256, 4), 256, 0, stream>>>(
        UB, UW2T, U2B, upd_b2, nullptr, 256, 256, 256, 0);
    k_ln<<<16384, 64, 0, stream>>>(HMP, U2B, 1, HMP, lnm_g, lnm_b);
    if (step == 2) {
      k_halt1<<<dim3(32, 16), 64, 0, stream>>>(HMP, PS);
      k_halt2<<<16, 64, 0, stream>>>(PS, halt_w, halt_b, HP);
      k_kl<<<1, 1, 0, stream>>>(HP, klout);
      k_outmp<<<16384, 64, 0, stream>>>(HMP, HP, OUTMP, 0);
    } else if (step == 3) {
      k_outmp<<<16384, 64, 0, stream>>>(HMP, HP, OUTMP, 1);
    }
  }

  // 6) retrieval: QKV GEMM; fully-fused sparse top-8 attention; out proj
  gemm_bt<GF_BIAS><<<dim3(128, 6), 256, 0, stream>>>(
      OUTMP, QKVW, QKV, QKVB, nullptr, 256, 256, 768, 0);
  k_fatopk<<<dim3(64, 16), 64, 0, stream>>>(QKV, ATT);
  gemm64<GF_BIAS | GF_RES><<<dim3(256, 4), 256, 0, stream>>>(
      ATT, OT, COMB, o_b, OUTMP, 256, 256, 256, 256);
  gemm64<GF_BIAS><<<dim3(256, 4), 256, 0, stream>>>(
      COMB, BCT, BROAD, bc_b, nullptr, 256, 256, 256, 0);

  // 7) final = LN(local + broad) in place; logits = final @ head_w (f32 out)
  k_ln<<<65536, 64, 0, stream>>>(LOCb, BROAD, 2, LOCb, lnf_g, lnf_b);
  gemm_bt<GF_F32OUT><<<dim3(512, 2), 256, 0, stream>>>(
      LOCb, HEADT, out, nullptr, nullptr, 256, 256, 256, 0);
}

// Round 7
// 467.874 us; speedup vs baseline: 1.3618x; 1.0420x over previous
//
#include <hip/hip_runtime.h>
#include <math.h>

// ---------------------------------------------------------------------------
// B=16, T=4096, D=256, V=256, PATCH=4, Np=1024, BN=16384
// All GEMMs: C[M,N] = A[M,256] @ Bt[N,256]^T (+epilogue), bf16 inputs, K=256.
// LDS tiles XOR-swizzled (T2). Sparse top-8 attention fully fused; 4 waves
// per q-tile split the causal K-scan (R6 was 1 wave -> latency-bound).
// ---------------------------------------------------------------------------

typedef __bf16 bf16_t;
typedef bf16_t bf16x8 __attribute__((ext_vector_type(8)));
typedef bf16_t bf16x4 __attribute__((ext_vector_type(4)));
typedef float f32x4 __attribute__((ext_vector_type(4)));

#define GF_BIAS 1
#define GF_GELU 4
#define GF_RES 8
#define GF_F32OUT 32

__device__ __forceinline__ float gelu_exact(float x) {
  return 0.5f * x * (1.0f + erff(x * 0.7071067811865475f));
}

__device__ __forceinline__ float sigm(float x) { return 1.f / (1.f + expf(-x)); }

__device__ __forceinline__ float wave_sum(float v) {
#pragma unroll
  for (int o = 32; o; o >>= 1) v += __shfl_xor(v, o, 64);
  return v;
}

__device__ __forceinline__ void gload16(const void* g, void* l) {
  __builtin_amdgcn_global_load_lds(
      (const __attribute__((address_space(1))) void*)g,
      (__attribute__((address_space(3))) void*)l, 16, 0, 0);
}

// sortable u64 key: (order-preserving f32 map) << 32 | (0x7FFFFFFF - m)
// larger key == (larger score, then lower index). Key 0 == empty slot.
__device__ __forceinline__ unsigned long long skey(float s, int m) {
  unsigned u = __float_as_uint(s);
  u ^= (u & 0x80000000u) ? 0xFFFFFFFFu : 0x80000000u;
  return ((unsigned long long)u << 32) | (unsigned)(0x7FFFFFFF - m);
}

// ---------------- bf16 MFMA GEMM: 128x128 tile, 4 waves, BK=64, swizzled ----
template<int FLAGS>
__global__ __launch_bounds__(256)
void gemm_bt(const bf16_t* __restrict__ A, const bf16_t* __restrict__ Bt,
             void* __restrict__ Cv, const float* __restrict__ bias,
             const bf16_t* __restrict__ res,
             int lda, int ldb, int ldc, int ldr)
{
  __shared__ __align__(16) bf16_t As[128][64];
  __shared__ __align__(16) bf16_t Bs[128][64];
  const int m0 = blockIdx.x * 128, n0 = blockIdx.y * 128;
  const int tid = threadIdx.x, lane = tid & 63, wave = tid >> 6;
  const int wm = (wave >> 1) << 6, wn = (wave & 1) << 6;
  const int lr = lane & 15, lg = lane >> 4;
  const int cx = lane & 7;

  // staging: linear LDS dest (wave base + lane*16); swizzle the global source
  const int srow = wave * 32 + (lane >> 3);
  const int scol = (((lane & 7) ^ ((lane >> 3) & 7)) * 8);
  const bf16_t* ga = A  + (long long)(m0 + srow) * lda + scol;
  const bf16_t* gb = Bt + (long long)(n0 + srow) * ldb + scol;
  char* lA = (char*)(&As[srow][0]) + (lane & 7) * 16;
  char* lB = (char*)(&Bs[srow][0]) + (lane & 7) * 16;

  f32x4 acc[4][4] = {};

#pragma unroll
  for (int kt = 0; kt < 4; kt++) {
    const int ko = kt * 64;
#pragma unroll
    for (int q = 0; q < 4; q++) {
      gload16(ga + (long long)q * 8 * lda + ko, lA + q * 1024);
      gload16(gb + (long long)q * 8 * ldb + ko, lB + q * 1024);
    }
    __syncthreads();
#pragma unroll
    for (int kk = 0; kk < 2; kk++) {
      const int co = ((kk * 4 + lg) ^ cx) << 4;  // swizzled 16B chunk offset
      bf16x8 af[4], bfv[4];
#pragma unroll
      for (int i = 0; i < 4; i++)
        af[i]  = *(const bf16x8*)((char*)As + (wm + i * 16 + lr) * 128 + co);
#pragma unroll
      for (int j = 0; j < 4; j++)
        bfv[j] = *(const bf16x8*)((char*)Bs + (wn + j * 16 + lr) * 128 + co);
#pragma unroll
      for (int i = 0; i < 4; i++)
#pragma unroll
        for (int j = 0; j < 4; j++)
          acc[i][j] = __builtin_amdgcn_mfma_f32_16x16x32_bf16(af[i], bfv[j], acc[i][j], 0, 0, 0);
    }
    if (kt < 3) __syncthreads();
  }

#pragma unroll
  for (int i = 0; i < 4; i++) {
#pragma unroll
    for (int j = 0; j < 4; j++) {
      const int col = n0 + wn + j * 16 + lr;
      const float bval = (FLAGS & GF_BIAS) ? bias[col] : 0.f;
#pragma unroll
      for (int e = 0; e < 4; e++) {
        const int row = m0 + wm + i * 16 + lg * 4 + e;
        float v = acc[i][j][e] + bval;
        if (FLAGS & GF_RES) v += (float)res[(long long)row * ldr + col];
        if (FLAGS & GF_GELU) v = gelu_exact(v);
        const long long ci = (long long)row * ldc + col;
        if (FLAGS & GF_F32OUT) ((float*)Cv)[ci] = v;
        else                   ((bf16_t*)Cv)[ci] = (bf16_t)v;
      }
    }
  }
}

// ---------------- bf16 MFMA GEMM: 64x64 tile, 4 waves, BK=64, swizzled ------
template<int FLAGS>
__global__ __launch_bounds__(256)
void gemm64(const bf16_t* __restrict__ A, const bf16_t* __restrict__ Bt,
            void* __restrict__ Cv, const float* __restrict__ bias,
            const bf16_t* __restrict__ res,
            int lda, int ldb, int ldc, int ldr)
{
  __shared__ __align__(16) bf16_t As[64][64];
  __shared__ __align__(16) bf16_t Bs[64][64];
  const int m0 = blockIdx.x * 64, n0 = blockIdx.y * 64;
  const int tid = threadIdx.x, lane = tid & 63, wave = tid >> 6;
  const int wm = (wave >> 1) * 32, wn = (wave & 1) * 32;
  const int lr = lane & 15, lg = lane >> 4;
  const int cx = lane & 7;

  const int srow = tid >> 3;            // 0..31 (two 32-row rounds)
  const int scol = (((tid & 7) ^ (srow & 7)) * 8);   // pre-swizzled source
  const bf16_t* ga = A  + (long long)(m0 + srow) * lda + scol;
  const bf16_t* gb = Bt + (long long)(n0 + srow) * ldb + scol;
  char* lA = (char*)As + tid * 16;
  char* lB = (char*)Bs + tid * 16;

  f32x4 acc[2][2] = {};

#pragma unroll
  for (int kt = 0; kt < 4; kt++) {
    const int ko = kt * 64;
    gload16(ga + ko, lA);
    gload16(ga + 32LL * lda + ko, lA + 4096);
    gload16(gb + ko, lB);
    gload16(gb + 32LL * ldb + ko, lB + 4096);
    __syncthreads();
#pragma unroll
    for (int kk = 0; kk < 2; kk++) {
      const int co = ((kk * 4 + lg) ^ cx) << 4;
      bf16x8 af[2], bfv[2];
#pragma unroll
      for (int i = 0; i < 2; i++)
        af[i]  = *(const bf16x8*)((char*)As + (wm + i * 16 + lr) * 128 + co);
#pragma unroll
      for (int j = 0; j < 2; j++)
        bfv[j] = *(const bf16x8*)((char*)Bs + (wn + j * 16 + lr) * 128 + co);
#pragma unroll
      for (int i = 0; i < 2; i++)
#pragma unroll
        for (int j = 0; j < 2; j++)
          acc[i][j] = __builtin_amdgcn_mfma_f32_16x16x32_bf16(af[i], bfv[j], acc[i][j], 0, 0, 0);
    }
    if (kt < 3) __syncthreads();
  }

#pragma unroll
  for (int i = 0; i < 2; i++) {
#pragma unroll
    for (int j = 0; j < 2; j++) {
      const int col = n0 + wn + j * 16 + lr;
      const float bval = (FLAGS & GF_BIAS) ? bias[col] : 0.f;
#pragma unroll
      for (int e = 0; e < 4; e++) {
        const int row = m0 + wm + i * 16 + lg * 4 + e;
        float v = acc[i][j][e] + bval;
        if (FLAGS & GF_RES) v += (float)res[(long long)row * ldr + col];
        if (FLAGS & GF_GELU) v = gelu_exact(v);
        const long long ci = (long long)row * ldc + col;
        if (FLAGS & GF_F32OUT) ((float*)Cv)[ci] = v;
        else                   ((bf16_t*)Cv)[ci] = (bf16_t)v;
      }
    }
  }
}

// ---------------- fused sparse top-8 attention (4 waves / q-tile) -----------
// Block = 256 thr handles 16 Q-rows. Wave w scans K-tiles kt ≡ w (mod 4):
// swapped QK^T (mfma(K,Q)) -> lane (lr,lg) holds scores for Q-row lr, K-rows
// kt*16+lg*4+e. Lane-local u64 top-8 -> in-wave 4-lane merge -> LDS ->
// wave 0 merges 4 waves' lists -> softmax weights to LDS -> all-wave V gather.
__global__ __launch_bounds__(256)
void k_fatopk(const bf16_t* __restrict__ QKV, bf16_t* __restrict__ O) {
  __shared__ unsigned long long cand[4][16][8];
  __shared__ float wrow[16][8];
  __shared__ int   irow[16][8];
  const int b = blockIdx.y;
  const int qw = (int)((blockIdx.x + ((unsigned)(b * 21) & 63u)) & 63u);  // balance
  const int tid = threadIdx.x;
  const int wid = tid >> 6;
  const int lane = tid & 63;
  const int lr = lane & 15, lg = lane >> 4;
  const bf16_t* Qp = QKV + (long long)b * (1024LL * 768);
  const bf16_t* Kp = Qp + 256;
  const bf16_t* Vp = Qp + 512;
  const int q0 = qw * 16;
  const int qrow = q0 + lr;

  // Q fragments hoisted to registers (32 VGPR)
  bf16x8 bq[8];
#pragma unroll
  for (int s = 0; s < 8; s++)
    bq[s] = *(const bf16x8*)(Qp + (long long)qrow * 768 + s * 32 + lg * 8);

  unsigned long long kv[8] = {0ull, 0ull, 0ull, 0ull, 0ull, 0ull, 0ull, 0ull};

#define INS8(KEY) {                                                     \
    const unsigned long long k_ = (KEY);                                \
    if (k_ > kv[7]) {                                                   \
      kv[7] = k_;                                                       \
      _Pragma("unroll")                                                 \
      for (int j_ = 7; j_ > 0; j_--)                                    \
        if (kv[j_] > kv[j_-1]) {                                        \
          const unsigned long long t_ = kv[j_];                         \
          kv[j_] = kv[j_-1]; kv[j_-1] = t_;                             \
        }                                                               \
    }                                                                   \
  }

  const int klim = qw + 1;  // causal: 16-row K-tiles 0..qw, wave-strided by 4
  for (int kt = wid; kt < klim; kt += 4) {
    const bf16_t* ka = Kp + (long long)(kt * 16 + lr) * 768 + lg * 8;
    bf16x8 af[8];
#pragma unroll
    for (int s = 0; s < 8; s++) af[s] = *(const bf16x8*)(ka + s * 32);
    f32x4 a0 = {}, a1 = {};
#pragma unroll
    for (int s = 0; s < 8; s += 2) {
      a0 = __builtin_amdgcn_mfma_f32_16x16x32_bf16(af[s],     bq[s],     a0, 0, 0, 0);
      a1 = __builtin_amdgcn_mfma_f32_16x16x32_bf16(af[s + 1], bq[s + 1], a1, 0, 0, 0);
    }
#pragma unroll
    for (int e = 0; e < 4; e++) {
      const int m = kt * 16 + lg * 4 + e;
      if (m <= qrow) INS8(skey((a0[e] + a1[e]) * 0.0625f, m));
    }
  }
#undef INS8

  // in-wave merge across the 4 lanes sharing lr; store sorted keys to LDS
#pragma unroll
  for (int r = 0; r < 8; r++) {
    unsigned long long mk = kv[0];
    unsigned long long ok = __shfl_xor(mk, 16, 64); if (ok > mk) mk = ok;
    ok = __shfl_xor(mk, 32, 64); if (ok > mk) mk = ok;
    if (lg == 0) cand[wid][lr][r] = mk;
    if (kv[0] == mk && mk != 0ull) {
#pragma unroll
      for (int j = 0; j < 7; j++) kv[j] = kv[j + 1];
      kv[7] = 0ull;
    }
  }
  __syncthreads();

  // wave 0: cross-wave merge (lane (lr,lg) owns wave lg's list for row lr)
  if (wid == 0) {
    unsigned long long kv2[8];
#pragma unroll
    for (int j = 0; j < 8; j++) kv2[j] = cand[lg][lr][j];
    float wv[8]; int wi[8];
#pragma unroll
    for (int r = 0; r < 8; r++) {
      unsigned long long mk = kv2[0];
      unsigned long long ok = __shfl_xor(mk, 16, 64); if (ok > mk) mk = ok;
      ok = __shfl_xor(mk, 32, 64); if (ok > mk) mk = ok;
      if (mk != 0ull) {
        unsigned hi = (unsigned)(mk >> 32);
        hi ^= (hi & 0x80000000u) ? 0x80000000u : 0xFFFFFFFFu;
        wv[r] = __uint_as_float(hi);
        wi[r] = 0x7FFFFFFF - (int)(unsigned)(mk & 0xFFFFFFFFu);
      } else {
        wv[r] = 0.f; wi[r] = -1;
      }
      if (kv2[0] == mk && mk != 0ull) {
#pragma unroll
        for (int j = 0; j < 7; j++) kv2[j] = kv2[j + 1];
        kv2[7] = 0ull;
      }
    }
    const float mx = wv[0];
    float w8[8]; float den = 0.f;
#pragma unroll
    for (int j = 0; j < 8; j++) {
      w8[j] = (wi[j] >= 0) ? expf(wv[j] - mx) : 0.f;
      den += w8[j];
    }
    const float inv = 1.f / den;
    if (lg == 0) {
#pragma unroll
      for (int j = 0; j < 8; j++) {
        wrow[lr][j] = w8[j] * inv;
        irow[lr][j] = wi[j];
      }
    }
  }
  __syncthreads();

  // all-wave V gather: row rr = wid*4 + (lane>>4), 16-elem d-chunk per lane
  const int rr = wid * 4 + lg;
  const int c0 = (lane & 15) * 16;
  f32x4 av[4] = {};
#pragma unroll
  for (int j = 0; j < 8; j++) {
    const int idx = irow[rr][j];
    if (idx >= 0) {
      const float wj = wrow[rr][j];
      const bf16_t* vr = Vp + (long long)idx * 768 + c0;
      const bf16x8 v0 = *(const bf16x8*)vr;
      const bf16x8 v1 = *(const bf16x8*)(vr + 8);
#pragma unroll
      for (int e = 0; e < 4; e++) {
        av[0][e] = fmaf(wj, (float)v0[e],     av[0][e]);
        av[1][e] = fmaf(wj, (float)v0[4 + e], av[1][e]);
        av[2][e] = fmaf(wj, (float)v1[e],     av[2][e]);
        av[3][e] = fmaf(wj, (float)v1[4 + e], av[3][e]);
      }
    }
  }
  bf16_t* op = O + ((long long)b * 1024 + q0 + rr) * 256 + c0;
  bf16x8 o0, o1;
#pragma unroll
  for (int e = 0; e < 4; e++) {
    o0[e] = (bf16_t)av[0][e]; o0[4 + e] = (bf16_t)av[1][e];
    o1[e] = (bf16_t)av[2][e]; o1[4 + e] = (bf16_t)av[3][e];
  }
  *(bf16x8*)op = o0;
  *(bf16x8*)(op + 8) = o1;
}

// ---------------- prep: weight transposes (f32->bf16), xe, fused biases -----
struct TD { const float* src; bf16_t* dst; int N; int k0; int ld; };  // k0<0: direct copy
struct PrepArgs {
  TD d[16];
  const float* emb; const float* pos; bf16_t* XE;
  const float* msg_b1; const float* msg_b2; const float* upd_w1; const float* upd_b1;
  const float* q_b; const float* k_b; const float* v_b;
  float* BIAS3; float* QKVB;
};

__global__ __launch_bounds__(256) void k_prep(PrepArgs pa) {
  const int y = blockIdx.y, x = blockIdx.x, d = threadIdx.x;
  if (y < 16) {
    TD t = pa.d[y];
    if (x >= t.N) return;
    if (t.k0 < 0) t.dst[(long long)x * 256 + d] = (bf16_t)t.src[(long long)x * t.ld + d];
    else          t.dst[(long long)x * 256 + d] = (bf16_t)t.src[(long long)(t.k0 + d) * t.ld + x];
  } else if (y == 16) {
    const int p = x >> 8, v = x & 255;
    pa.XE[(long long)x * 256 + d] = (bf16_t)(pa.emb[v * 256 + d] + pa.pos[p * 256 + d]);
  } else {
    if      (x == 0) pa.BIAS3[d] = pa.msg_b1[d];
    else if (x == 1) pa.BIAS3[256 + d] = 0.f;
    else if (x == 2) {
      // c1[d] = upd_b1[d] + sum_k msg_b2[k] * upd_w1[256+k][d]
      float acc = pa.upd_b1[d];
      for (int k = 0; k < 256; k++) acc += pa.msg_b2[k] * pa.upd_w1[(long long)(256 + k) * 256 + d];
      pa.BIAS3[512 + d] = acc;
    }
    else if (x == 3) pa.QKVB[d] = pa.q_b[d];
    else if (x == 4) pa.QKVB[256 + d] = pa.k_b[d];
    else if (x == 5) pa.QKVB[512 + d] = pa.v_b[d];
  }
}

// ---------------- GRU gate (bf16 gi table) -----------------------------------
__global__ __launch_bounds__(64)
void k_gru_gate(const int* __restrict__ x, const bf16_t* __restrict__ gitab,
                const bf16_t* __restrict__ GH, const float* __restrict__ bhh,
                bf16_t* __restrict__ H, bf16_t* __restrict__ LOC, int t)
{
  const int s = blockIdx.x, lane = threadIdx.x, d0 = lane * 4;
  const int v = x[s * 4 + t];
  const bf16_t* gi = gitab + (long long)(t * 256 + v) * 768;
  const bf16x4 g_r = *(const bf16x4*)(gi + d0);
  const bf16x4 g_z = *(const bf16x4*)(gi + 256 + d0);
  const bf16x4 g_n = *(const bf16x4*)(gi + 512 + d0);
  float hr[4], hz[4], hn[4], hp[4];
  if (t == 0) {
#pragma unroll
    for (int e = 0; e < 4; e++) {
      hr[e] = bhh[d0 + e]; hz[e] = bhh[256 + d0 + e]; hn[e] = bhh[512 + d0 + e];
      hp[e] = 0.f;
    }
  } else {
    const bf16_t* gh = GH + (long long)s * 768;
    const bf16x4 a = *(const bf16x4*)(gh + d0);
    const bf16x4 b4 = *(const bf16x4*)(gh + 256 + d0);
    const bf16x4 c4 = *(const bf16x4*)(gh + 512 + d0);
    const bf16x4 hv = *(const bf16x4*)(H + (long long)s * 256 + d0);
#pragma unroll
    for (int e = 0; e < 4; e++) { hr[e] = a[e]; hz[e] = b4[e]; hn[e] = c4[e]; hp[e] = hv[e]; }
  }
  bf16x4 ho;
#pragma unroll
  for (int e = 0; e < 4; e++) {
    const float r = sigm((float)g_r[e] + hr[e]);
    const float zz = sigm((float)g_z[e] + hz[e]);
    const float nn = tanhf((float)g_n[e] + r * hn[e]);
    ho[e] = (bf16_t)((1.f - zz) * nn + zz * hp[e]);
  }
  *(bf16x4*)(H + (long long)s * 256 + d0) = ho;
  *(bf16x4*)(LOC + ((long long)s * 4 + t) * 256 + d0) = ho;
}

// ---------------- LN (generic, 64 threads/row) ------------------------------
__global__ __launch_bounds__(64)
void k_ln(const bf16_t* __restrict__ X, const bf16_t* __restrict__ ADD, int addmode,
          bf16_t* __restrict__ OUT, const float* __restrict__ g,
          const float* __restrict__ b)
{
  const long long r = blockIdx.x;
  const int d0 = threadIdx.x * 4;
  const bf16x4 xv = *(const bf16x4*)(X + r * 256 + d0);
  float xf[4];
#pragma unroll
  for (int e = 0; e < 4; e++) xf[e] = (float)xv[e];
  if (addmode == 1) {
    const bf16x4 av = *(const bf16x4*)(ADD + r * 256 + d0);
#pragma unroll
    for (int e = 0; e < 4; e++) xf[e] += (float)av[e];
  } else if (addmode == 2) {
    const bf16x4 av = *(const bf16x4*)(ADD + (r >> 2) * 256 + d0);
#pragma unroll
    for (int e = 0; e < 4; e++) xf[e] += (float)av[e];
  }
  const float mean = wave_sum(xf[0] + xf[1] + xf[2] + xf[3]) * (1.f / 256.f);
  float q = 0.f;
#pragma unroll
  for (int e = 0; e < 4; e++) { const float dx = xf[e] - mean; q += dx * dx; }
  const float rstd = rsqrtf(wave_sum(q) * (1.f / 256.f) + 1e-5f);
  const float4 gv = *(const float4*)(g + d0);
  const float4 bv = *(const float4*)(b + d0);
  const float gg[4] = {gv.x, gv.y, gv.z, gv.w};
  const float bb[4] = {bv.x, bv.y, bv.z, bv.w};
  bf16x4 ov;
#pragma unroll
  for (int e = 0; e < 4; e++) ov[e] = (bf16_t)((xf[e] - mean) * rstd * gg[e] + bb[e]);
  *(bf16x4*)(OUT + r * 256 + d0) = ov;
}

// ---------------- LN + out_mp accumulate (step 3) ---------------------------
// y = LN(X + ADD); OUTMP += (1 - HP[b]) * y   (HMP itself is dead after this)
__global__ __launch_bounds__(64)
void k_ln_out(const bf16_t* __restrict__ X, const bf16_t* __restrict__ ADD,
              bf16_t* __restrict__ OUTMP, const float* __restrict__ HP,
              const float* __restrict__ g, const float* __restrict__ b)
{
  const long long r = blockIdx.x;
  const int d0 = threadIdx.x * 4;
  const bf16x4 xv = *(const bf16x4*)(X + r * 256 + d0);
  const bf16x4 avv = *(const bf16x4*)(ADD + r * 256 + d0);
  float xf[4];
#pragma unroll
  for (int e = 0; e < 4; e++) xf[e] = (float)xv[e] + (float)avv[e];
  const float mean = wave_sum(xf[0] + xf[1] + xf[2] + xf[3]) * (1.f / 256.f);
  float q = 0.f;
#pragma unroll
  for (int e = 0; e < 4; e++) { const float dx = xf[e] - mean; q += dx * dx; }
  const float rstd = rsqrtf(wave_sum(q) * (1.f / 256.f) + 1e-5f);
  const float4 gv = *(const float4*)(g + d0);
  const float4 bv = *(const float4*)(b + d0);
  const float gg[4] = {gv.x, gv.y, gv.z, gv.w};
  const float bb[4] = {bv.x, bv.y, bv.z, bv.w};
  const float rem = 1.f - HP[(int)(r >> 10)];
  const bf16x4 pv = *(const bf16x4*)(OUTMP + r * 256 + d0);
  bf16x4 ov;
#pragma unroll
  for (int e = 0; e < 4; e++) {
    const float y = (xf[e] - mean) * rstd * gg[e] + bb[e];
    ov[e] = (bf16_t)((float)pv[e] + rem * y);
  }
  *(bf16x4*)(OUTMP + r * 256 + d0) = ov;
}

// ---------------- fused patch-LN + mean over 4 rows -------------------------
__global__ __launch_bounds__(64)
void k_lnp4(bf16_t* __restrict__ LOC, bf16_t* __restrict__ SUMB,
            const float* __restrict__ g, const float* __restrict__ b)
{
  const long long s = blockIdx.x;
  const int d0 = threadIdx.x * 4;
  const float4 gv = *(const float4*)(g + d0);
  const float4 bv = *(const float4*)(b + d0);
  const float gg[4] = {gv.x, gv.y, gv.z, gv.w};
  const float bb[4] = {bv.x, bv.y, bv.z, bv.w};
  float accd[4] = {0.f, 0.f, 0.f, 0.f};
#pragma unroll
  for (int t = 0; t < 4; t++) {
    bf16_t* row = LOC + (s * 4 + t) * 256 + d0;
    const bf16x4 xv = *(const bf16x4*)row;
    float xf[4];
#pragma unroll
    for (int e = 0; e < 4; e++) xf[e] = (float)xv[e];
    const float mean = wave_sum(xf[0] + xf[1] + xf[2] + xf[3]) * (1.f / 256.f);
    float q = 0.f;
#pragma unroll
    for (int e = 0; e < 4; e++) { const float dx = xf[e] - mean; q += dx * dx; }
    const float rstd = rsqrtf(wave_sum(q) * (1.f / 256.f) + 1e-5f);
    bf16x4 ov;
#pragma unroll
    for (int e = 0; e < 4; e++) {
      const float y = (xf[e] - mean) * rstd * gg[e] + bb[e];
      ov[e] = (bf16_t)y;
      accd[e] += y;
    }
    *(bf16x4*)row = ov;
  }
  bf16x4 sv;
#pragma unroll
  for (int e = 0; e < 4; e++) sv[e] = (bf16_t)(accd[e] * 0.25f);
  *(bf16x4*)(SUMB + s * 256 + d0) = sv;
}

// ---------------- gelu-mix over window (reads fused A3) ---------------------
__global__ __launch_bounds__(64)
void k_gelumix(const bf16_t* __restrict__ A3, bf16_t* __restrict__ G)
{
  const long long s = blockIdx.x;
  const int n = (int)(s & 1023);
  const int d0 = threadIdx.x * 4;
  const bf16x4 av = *(const bf16x4*)(A3 + s * 768 + d0);
  float a[4];
#pragma unroll
  for (int e = 0; e < 4; e++) a[e] = (float)av[e];
  float acc[4] = {0.f, 0.f, 0.f, 0.f};
  const bf16_t* bbase = A3 + s * 768 + 256 + d0;
#pragma unroll
  for (int w = 0; w <= 4; w++) {
    if (n >= w) {
      const bf16x4 bn = *(const bf16x4*)(bbase - (long long)w * 768);
#pragma unroll
      for (int e = 0; e < 4; e++) acc[e] += gelu_exact(a[e] + (float)bn[e]);
    } else {
#pragma unroll
      for (int e = 0; e < 4; e++) acc[e] += gelu_exact(a[e]);
    }
  }
  bf16x4 ov;
#pragma unroll
  for (int e = 0; e < 4; e++) ov[e] = (bf16_t)(acc[e] * 0.2f);
  *(bf16x4*)(G + s * 256 + d0) = ov;
}

// ---------------- halting ----------------------------------------------------
__global__ __launch_bounds__(64)
void k_halt1(const bf16_t* __restrict__ Hm, float* __restrict__ PS) {
  const int c = blockIdx.x, b = blockIdx.y, d0 = threadIdx.x * 4;
  float acc[4] = {0.f, 0.f, 0.f, 0.f};
  const bf16_t* base = Hm + ((long long)b * 1024 + c * 32) * 256 + d0;
#pragma unroll 4
  for (int n = 0; n < 32; n++) {
    const bf16x4 hv = *(const bf16x4*)(base + (long long)n * 256);
#pragma unroll
    for (int e = 0; e < 4; e++) acc[e] += (float)hv[e];
  }
  float4 o4; o4.x = acc[0]; o4.y = acc[1]; o4.z = acc[2]; o4.w = acc[3];
  *(float4*)(PS + ((long long)b * 32 + c) * 256 + d0) = o4;
}

__global__ __launch_bounds__(64)
void k_halt2(const float* __restrict__ PS, const float* __restrict__ hw,
             const float* __restrict__ hb, float* __restrict__ HP) {
  const int b = blockIdx.x, d0 = threadIdx.x * 4;
  float acc[4] = {0.f, 0.f, 0.f, 0.f};
  for (int c = 0; c < 32; c++) {
    const float4 p4 = *(const float4*)(PS + ((long long)b * 32 + c) * 256 + d0);
    acc[0] += p4.x; acc[1] += p4.y; acc[2] += p4.z; acc[3] += p4.w;
  }
  const float4 w4 = *(const float4*)(hw + d0);
  float val = (acc[0] * w4.x + acc[1] * w4.y + acc[2] * w4.z + acc[3] * w4.w) * (1.f / 1024.f);
  val = wave_sum(val);
  if (threadIdx.x == 0) HP[b] = sigm(val + hb[0]);
}

__global__ void k_kl(const float* __restrict__ HP, float* __restrict__ out) {
  float s = 0.f;
  for (int b = 0; b < 16; b++) s += HP[b];
  const float hpm = s * (1.f / 16.f);
  const float l8 = logf(1e-8f);
  const float p0 = 0.2f, p1 = 0.16f, p2 = 0.128f, p3 = 0.1024f;
  const float kl = p0 * (logf(p0) - l8)
                 + p1 * (logf(p1) - l8)
                 + p2 * (logf(p2) - logf(hpm + 1e-8f))
                 + p3 * (logf(p3) - logf(1.f + 1e-8f));
  out[0] = kl * 0.25f;
}

__global__ __launch_bounds__(64)
void k_outmp(const bf16_t* __restrict__ Hm, const float* __restrict__ HP,
             bf16_t* __restrict__ O, int acc) {
  const long long s = blockIdx.x;
  const int d0 = threadIdx.x * 4;
  const int b = (int)(s >> 10);
  const float hp = HP[b];
  const bf16x4 hv = *(const bf16x4*)(Hm + s * 256 + d0);
  bf16x4 ov;
  if (acc) {
    const bf16x4 pv = *(const bf16x4*)(O + s * 256 + d0);
#pragma unroll
    for (int e = 0; e < 4; e++) ov[e] = (bf16_t)((float)pv[e] + (1.f - hp) * (float)hv[e]);
  } else {
#pragma unroll
    for (int e = 0; e < 4; e++) ov[e] = (bf16_t)(hp * (float)hv[e]);
  }
  *(bf16x4*)(O + s * 256 + d0) = ov;
}

// ---------------------------------------------------------------------------
extern "C" void kernel_launch(void* const* d_in, const int* in_sizes, int n_in,
                              void* d_out, int out_size, void* d_ws, size_t ws_size,
                              hipStream_t stream) {
  (void)in_sizes; (void)n_in; (void)ws_size;
  const int*   x      = (const int*)d_in[0];
  const float* emb    = (const float*)d_in[1];
  const float* pos    = (const float*)d_in[2];
  const float* wih    = (const float*)d_in[3];
  const float* whh    = (const float*)d_in[4];
  const float* bih    = (const float*)d_in[5];
  const float* bhh    = (const float*)d_in[6];
  const float* lnp_g  = (const float*)d_in[7];
  const float* lnp_b  = (const float*)d_in[8];
  const float* sum_w  = (const float*)d_in[9];
  const float* sum_b  = (const float*)d_in[10];
  const float* msg_w1 = (const float*)d_in[11];
  const float* msg_b1 = (const float*)d_in[12];
  const float* msg_w2 = (const float*)d_in[13];
  const float* msg_b2 = (const float*)d_in[14];
  const float* upd_w1 = (const float*)d_in[15];
  const float* upd_b1 = (const float*)d_in[16];
  const float* upd_w2 = (const float*)d_in[17];
  const float* upd_b2 = (const float*)d_in[18];
  const float* halt_w = (const float*)d_in[19];
  const float* halt_b = (const float*)d_in[20];
  const float* lnm_g  = (const float*)d_in[21];
  const float* lnm_b  = (const float*)d_in[22];
  const float* q_b    = (const float*)d_in[24];
  const float* k_b    = (const float*)d_in[26];
  const float* v_b    = (const float*)d_in[28];
  const float* o_b    = (const float*)d_in[30];
  const float* bc_b   = (const float*)d_in[32];
  const float* lnf_g  = (const float*)d_in[33];
  const float* lnf_b  = (const float*)d_in[34];

  char* base = (char*)d_ws;
  size_t off = 0;
  auto alloc = [&](size_t bytes) -> void* {
    void* p = (void*)(base + off);
    off += (bytes + 255) & ~(size_t)255;
    return p;
  };
  const size_t SL2 = 16384ull * 256 * 2;   // bf16 activation slab (8 MiB)
  bf16_t* WIHT  = (bf16_t*)alloc(768 * 256 * 2);
  bf16_t* WHHT  = (bf16_t*)alloc(768 * 256 * 2);
  bf16_t* SUMT  = (bf16_t*)alloc(256 * 256 * 2);
  bf16_t* MW    = (bf16_t*)alloc(768 * 256 * 2);   // [msgW1self; msgW1neigh; updW1h]
  bf16_t* W2T   = (bf16_t*)alloc(256 * 256 * 2);
  bf16_t* W2NT  = (bf16_t*)alloc(256 * 256 * 2);   // msg_w2 direct (row-major)
  bf16_t* UW1MT = (bf16_t*)alloc(256 * 256 * 2);
  bf16_t* UW2T  = (bf16_t*)alloc(256 * 256 * 2);
  bf16_t* WCB   = (bf16_t*)alloc(256 * 256 * 2);   // (msg_w2 @ uw1m) in Bt form
  bf16_t* QKVW  = (bf16_t*)alloc(768 * 256 * 2);
  bf16_t* OT    = (bf16_t*)alloc(256 * 256 * 2);
  bf16_t* BCT   = (bf16_t*)alloc(256 * 256 * 2);
  bf16_t* HEADT = (bf16_t*)alloc(256 * 256 * 2);
  float*  BIAS3 = (float*)alloc(768 * 4);
  float*  QKVB  = (float*)alloc(768 * 4);
  bf16_t* XE    = (bf16_t*)alloc(1024ull * 256 * 2);
  bf16_t* GITAB = (bf16_t*)alloc(1024ull * 768 * 2);
  bf16_t* LOCb  = (bf16_t*)alloc(65536ull * 256 * 2);        // 32 MiB

  // --- 64 MiB overlay: GRU {GH,H} / phase-B {SUMB} / MP {A3} ---------------
  char*   SCR   = (char*)alloc(16ull * 1024 * 1024 * 4);     // 64 MiB
  bf16_t* GH    = (bf16_t*)SCR;                              // 24 MiB (GRU)
  bf16_t* H     = (bf16_t*)(SCR + 25165824);                 //  8 MiB (GRU)
  bf16_t* SUMB  = (bf16_t*)(SCR + 33554432);                 //  8 MiB (phase B)
  bf16_t* A3    = (bf16_t*)(SCR + 41943040);                 // 24 MiB (MP rounds)

  bf16_t* HMP   = (bf16_t*)alloc(SL2);
  bf16_t* G     = (bf16_t*)alloc(SL2);
  bf16_t* BROAD = (bf16_t*)alloc(SL2);
  bf16_t* UB    = (bf16_t*)alloc(SL2);   // later ATT
  bf16_t* U2B   = (bf16_t*)alloc(SL2);   // later COMB
  bf16_t* OUTMP = (bf16_t*)alloc(SL2);
  bf16_t* QKV   = (bf16_t*)alloc(16384ull * 768 * 2);        // 24 MiB
  float*  PS    = (float*)alloc(512ull * 256 * 4);
  float*  HP    = (float*)alloc(64);
  bf16_t* ATT   = UB;
  bf16_t* COMB  = U2B;
  float*  out   = (float*)d_out;
  float*  klout = out + (out_size - 1);

  // 1) prep: transposes + xe + fused biases
  PrepArgs pa;
  pa.d[0]  = { wih,                    WIHT,            768, 0,   768 };
  pa.d[1]  = { whh,                    WHHT,            768, 0,   768 };
  pa.d[2]  = { sum_w,                  SUMT,            256, 0,   256 };
  pa.d[3]  = { msg_w1,                 MW,              256, 0,   256 };
  pa.d[4]  = { msg_w1,                 MW + 256 * 256,  256, 256, 256 };
  pa.d[5]  = { upd_w1,                 MW + 512 * 256,  256, 0,   256 };
  pa.d[6]  = { msg_w2,                 W2T,             256, 0,   256 };
  pa.d[7]  = { upd_w1,                 UW1MT,           256, 256, 256 };
  pa.d[8]  = { upd_w2,                 UW2T,            256, 0,   256 };
  pa.d[9]  = { (const float*)d_in[23], QKVW,            256, 0,   256 };
  pa.d[10] = { (const float*)d_in[25], QKVW + 256*256,  256, 0,   256 };
  pa.d[11] = { (const float*)d_in[27], QKVW + 512*256,  256, 0,   256 };
  pa.d[12] = { (const float*)d_in[29], OT,              256, 0,   256 };
  pa.d[13] = { (const float*)d_in[31], BCT,             256, 0,   256 };
  pa.d[14] = { (const float*)d_in[35], HEADT,           256, 0,   256 };
  pa.d[15] = { msg_w2,                 W2NT,            256, -1,  256 };
  pa.emb = emb; pa.pos = pos; pa.XE = XE;
  pa.msg_b1 = msg_b1; pa.msg_b2 = msg_b2; pa.upd_w1 = upd_w1; pa.upd_b1 = upd_b1;
  pa.q_b = q_b; pa.k_b = k_b; pa.v_b = v_b;
  pa.BIAS3 = BIAS3; pa.QKVB = QKVB;
  k_prep<<<dim3(1024, 18), 256, 0, stream>>>(pa);

  // 1b) WCB[j][i] = sum_k uw1m[k][j] * msg_w2[i][k]  (Bt form of msg_w2@uw1m)
  gemm64<0><<<dim3(4, 4), 256, 0, stream>>>(
      UW1MT, W2NT, WCB, nullptr, nullptr, 256, 256, 256, 0);

  // 2) GRU input table (bf16): gi = (emb+pos) @ wih + bih
  gemm64<GF_BIAS><<<dim3(16, 12), 256, 0, stream>>>(
      XE, WIHT, GITAB, bih, nullptr, 256, 256, 768, 0);

  // 3) GRU over 4 steps (128-tile for the N=768 GEMMs: 768 blocks = 3/CU)
  k_gru_gate<<<16384, 64, 0, stream>>>(x, GITAB, GH, bhh, H, LOCb, 0);
  for (int t = 1; t < 4; t++) {
    gemm_bt<GF_BIAS><<<dim3(128, 6), 256, 0, stream>>>(
        H, WHHT, GH, bhh, nullptr, 256, 256, 768, 0);
    k_gru_gate<<<16384, 64, 0, stream>>>(x, GITAB, GH, bhh, H, LOCb, t);
  }

  // 4) local = LN(gout) in place + patch means; summaries GEMM
  k_lnp4<<<16384, 64, 0, stream>>>(LOCb, SUMB, lnp_g, lnp_b);
  gemm64<GF_BIAS><<<dim3(256, 4), 256, 0, stream>>>(
      SUMB, SUMT, HMP, sum_b, nullptr, 256, 256, 256, 0);

  // 5) message-passing rounds (WC fusion: msgs GEMM folded into UB GEMM)
  for (int step = 0; step < 4; step++) {
    gemm_bt<GF_BIAS><<<dim3(128, 6), 256, 0, stream>>>(
        HMP, MW, A3, BIAS3, nullptr, 256, 256, 768, 0);
    k_gelumix<<<16384, 64, 0, stream>>>(A3, G);
    gemm64<GF_RES | GF_GELU><<<dim3(256, 4), 256, 0, stream>>>(
        G, WCB, UB, nullptr, A3 + 512, 256, 256, 256, 768);
    gemm64<GF_BIAS><<<dim3(256, 4), 256, 0, stream>>>(
        UB, UW2T, U2B, upd_b2, nullptr, 256, 256, 256, 0);
    if (step == 3) {
      k_ln_out<<<16384, 64, 0, stream>>>(HMP, U2B, OUTMP, HP, lnm_g, lnm_b);
    } else {
      k_ln<<<16384, 64, 0, stream>>>(HMP, U2B, 1, HMP, lnm_g, lnm_b);
      if (step == 2) {
        k_halt1<<<dim3(32, 16), 64, 0, stream>>>(HMP, PS);
        k_halt2<<<16, 64, 0, stream>>>(PS, halt_w, halt_b, HP);
        k_kl<<<1, 1, 0, stream>>>(HP, klout);
        k_outmp<<<16384, 64, 0, stream>>>(HMP, HP, OUTMP, 0);
      }
    }
  }

  // 6) retrieval: QKV GEMM; fully-fused sparse top-8 attention; out proj
  gemm_bt<GF_BIAS><<<dim3(128, 6), 256, 0, stream>>>(
      OUTMP, QKVW, QKV, QKVB, nullptr, 256, 256, 768, 0);
  k_fatopk<<<dim3(64, 16), 256, 0, stream>>>(QKV, ATT);
  gemm64<GF_BIAS | GF_RES><<<dim3(256, 4), 256, 0, stream>>>(
      ATT, OT, COMB, o_b, OUTMP, 256, 256, 256, 256);
  gemm64<GF_BIAS><<<dim3(256, 4), 256, 0, stream>>>(
      COMB, BCT, BROAD, bc_b, nullptr, 256, 256, 256, 0);

  // 7) final = LN(local + broad) in place; logits = final @ head_w (f32 out)
  k_ln<<<65536, 64, 0, stream>>>(LOCb, BROAD, 2, LOCb, lnf_g, lnf_b);
  gemm_bt<GF_F32OUT><<<dim3(512, 2), 256, 0, stream>>>(
      LOCb, HEADT, out, nullptr, nullptr, 256, 256, 256, 0);
}